// Round 5
// baseline (587.025 us; speedup 1.0000x reference)
//
#include <hip/hip_runtime.h>

#define DD 256
#define HH 8
#define CC 32

typedef __attribute__((ext_vector_type(8))) short short8;
typedef __attribute__((ext_vector_type(4))) float f32x4;

static __device__ __forceinline__ unsigned short f2b(float f){
  unsigned u = __float_as_uint(f);
  u = u + 0x7FFFu + ((u >> 16) & 1u);          // RNE
  return (unsigned short)(u >> 16);
}
static __device__ __forceinline__ float b2f(unsigned short s){
  return __uint_as_float(((unsigned)s) << 16);
}

// ---------------- utility ----------------
__global__ void k_zero_i(int* p, int n){ int i=blockIdx.x*blockDim.x+threadIdx.x; if(i<n) p[i]=0; }

// ---------------- CSR build ----------------
__global__ void k_count(const int* __restrict__ dstE, int E, int N, int* cnt){
  int e=blockIdx.x*blockDim.x+threadIdx.x;
  if(e<E+N){ int d=(e<E)? dstE[e] : (e-E); atomicAdd(&cnt[d],1); }
}

__global__ __launch_bounds__(1024) void k_scan(const int* __restrict__ cnt, int N, int* row_off, int* cursor){
  __shared__ int part[1024];
  int t=threadIdx.x;
  int chunk=(N+1023)>>10;
  int s=0;
  for(int j=0;j<chunk;j++){ int i=t*chunk+j; if(i<N) s+=cnt[i]; }
  part[t]=s; __syncthreads();
  for(int off=1; off<1024; off<<=1){
    int v=(t>=off)? part[t-off]:0;
    __syncthreads();
    part[t]+=v;
    __syncthreads();
  }
  int run=(t==0)?0:part[t-1];
  for(int j=0;j<chunk;j++){ int i=t*chunk+j; if(i<N){ row_off[i]=run; cursor[i]=run; run+=cnt[i]; } }
  if(t==1023) row_off[N]=part[1023];
}

// emits e->pos mapping (epos) and CSR-ordered sources (esrc)
__global__ void k_fill(const int* __restrict__ srcE, const int* __restrict__ dstE, int E, int N,
                       int* cursor, int* epos, int* esrc){
  int e=blockIdx.x*blockDim.x+threadIdx.x;
  if(e>=E+N) return;
  int s,d;
  if(e<E){ s=srcE[e]; d=dstE[e]; } else { s=e-E; d=s; }
  int pos=atomicAdd(&cursor[d],1);
  epos[e]=pos; esrc[pos]=s;
}

// ---------------- weight transpose + bf16 convert: Wt[c][k] = W[k][c] ----------------
__global__ void k_cvt_wT(const float* __restrict__ W, unsigned short* __restrict__ Wt){
  int c=blockIdx.x, k=threadIdx.x;
  Wt[(size_t)c*DD+k] = f2b(W[(size_t)k*DD+c]);
}

// ---------------- folded logit weights ----------------
__global__ void k_pre(const float* __restrict__ Wd, const float* __restrict__ as_,
                      const float* __restrict__ We, const float* __restrict__ ae,
                      const float* __restrict__ te,
                      float* wd_as, float* v_e, float* t_a){
  int t=threadIdx.x;
  for(int idx=t; idx<DD*HH; idx+=256){
    int k=idx>>3, h=idx&7;
    const float* w=&Wd[k*DD+h*CC]; const float* a=&as_[h*CC];
    float s=0;
    #pragma unroll
    for(int c=0;c<CC;c++) s+=w[c]*a[c];
    wd_as[idx]=s;
  }
  for(int idx=t; idx<16*HH; idx+=256){
    int k=idx>>3, h=idx&7;
    const float* w=&We[k*DD+h*CC]; const float* a=&ae[h*CC];
    float s=0;
    #pragma unroll
    for(int c=0;c<CC;c++) s+=w[c]*a[c];
    v_e[idx]=s;
  }
  for(int idx=t; idx<7*HH; idx+=256){
    int k=idx>>3, h=idx&7;
    const float* w=&te[k*DD+h*CC]; const float* a=&ae[h*CC];
    float s=0;
    #pragma unroll
    for(int c=0;c<CC;c++) s+=w[c]*a[c];
    t_a[idx]=s;
  }
}

// ---------------- x -> bf16 + a_i = x @ wd_as ----------------
__global__ __launch_bounds__(256) void k_cvt_x(const float* __restrict__ xin, const float* __restrict__ wd_as,
                        unsigned short* __restrict__ xb, float* __restrict__ a_i, int N){
  __shared__ float red[DD*HH];     // [k][h] 8KB
  __shared__ float part[8][8];
  int n=blockIdx.x, tid=threadIdx.x;
  float v=xin[(size_t)n*DD+tid];
  xb[(size_t)n*DD+tid]=f2b(v);
  #pragma unroll
  for(int h=0;h<HH;h++) red[tid*HH+h]=v*wd_as[tid*HH+h];
  __syncthreads();
  if(tid<64){
    int h=tid&7, ch=tid>>3;
    float s=0.f;
    for(int k=ch*32;k<ch*32+32;k++) s+=red[k*HH+h];
    part[ch][h]=s;
  }
  __syncthreads();
  if(tid<8){
    float s=0.f;
    #pragma unroll
    for(int ch=0;ch<8;ch++) s+=part[ch][tid];
    a_i[(size_t)n*HH+tid]=s;
  }
}

// ---------------- a_j[n,h] = sum_c ys[n,32h+c]*ad[h,c] (ys bf16) ----------------
__global__ void k_aj(const unsigned short* __restrict__ ysb, const float* __restrict__ ad,
                     float* __restrict__ a_j, int N){
  int n=blockIdx.x, tid=threadIdx.x;
  float p=b2f(ysb[(size_t)n*DD+tid])*ad[tid];
  #pragma unroll
  for(int off=16;off>0;off>>=1) p+=__shfl_xor(p,off);
  if((tid&31)==0) a_j[(size_t)n*HH+(tid>>5)]=p;
}

// ---------------- bf16 MFMA GEMM: C[N,256] = A_bf16[N,256] @ B (Bt = B^T bf16) ----------------
// tile 128x128, BK=32, 4 waves; wave w -> 64x64 quadrant (wr=w>>1, wc=w&1), 4x4 MFMA frags.
// Register-prefetch software pipeline: next K-tile's global loads issue between
// LDS-write barrier and the MFMA block, so HBM latency hides under compute.
// LDS: 16B granules; (row r, granule kc) data stored at slot r*4 + (kc ^ ((r>>1)&3)).
template<bool OUTBF16, bool BIAS>
__global__ __launch_bounds__(256) void k_gemm_mfma(const unsigned short* __restrict__ A,
                                                   const unsigned short* __restrict__ Bt,
                                                   const float* __restrict__ bia1, const float* __restrict__ bia2,
                                                   void* __restrict__ Cout, int N){
  __shared__ char lds[16384];   // As 128x32 (8KB) + Bs 128x32 (8KB)
  int tid=threadIdx.x;
  int w=tid>>6, l=tid&63;
  int wr=w>>1, wc=w&1;
  int row0=blockIdx.y*128, col0=blockIdx.x*128;

  // staging: thread t -> (r=t>>2, kc=t&3); handles rows r and r+64 (same for B cols)
  int sr=tid>>2, skc=tid&3;
  int kcs=skc^((sr>>1)&3);             // same xor for sr+64 (since +32 even)
  int slot1=sr*4+skc, slot2=(sr+64)*4+skc;
  int gr1=row0+sr, gr2=row0+64+sr;
  size_t boff1=(size_t)(col0+sr)*DD, boff2=(size_t)(col0+64+sr)*DD;

  int x15=l&15;
  int lp=x15*64 + ((l>>4)^((x15>>1)&3))*16;

  f32x4 acc[4][4];
  #pragma unroll
  for(int i=0;i<4;i++)
    #pragma unroll
    for(int jj=0;jj<4;jj++) acc[i][jj]=(f32x4)0.f;

  const short8 zero8=(short8)0;
  short8 av1,av2,bv1,bv2;
  av1 = (gr1<N) ? *(const short8*)&A[(size_t)gr1*DD + kcs*8] : zero8;
  av2 = (gr2<N) ? *(const short8*)&A[(size_t)gr2*DD + kcs*8] : zero8;
  bv1 = *(const short8*)&Bt[boff1 + kcs*8];
  bv2 = *(const short8*)&Bt[boff2 + kcs*8];

  for(int kt=0;kt<DD;kt+=32){
    __syncthreads();
    *(short8*)(lds + slot1*16) = av1;
    *(short8*)(lds + slot2*16) = av2;
    *(short8*)(lds + 8192 + slot1*16) = bv1;
    *(short8*)(lds + 8192 + slot2*16) = bv2;
    __syncthreads();
    if(kt+32<DD){
      int ko=kt+32+kcs*8;
      av1 = (gr1<N) ? *(const short8*)&A[(size_t)gr1*DD + ko] : zero8;
      av2 = (gr2<N) ? *(const short8*)&A[(size_t)gr2*DD + ko] : zero8;
      bv1 = *(const short8*)&Bt[boff1 + ko];
      bv2 = *(const short8*)&Bt[boff2 + ko];
    }
    short8 af[4], bf[4];
    #pragma unroll
    for(int mf=0;mf<4;mf++) af[mf]=*(short8*)(lds + (64*wr+16*mf)*64 + lp);
    #pragma unroll
    for(int nf=0;nf<4;nf++) bf[nf]=*(short8*)(lds + 8192 + (64*wc+16*nf)*64 + lp);
    #pragma unroll
    for(int mf=0;mf<4;mf++)
      #pragma unroll
      for(int nf=0;nf<4;nf++)
        acc[mf][nf]=__builtin_amdgcn_mfma_f32_16x16x32_bf16(af[mf],bf[nf],acc[mf][nf],0,0,0);
  }

  int lcol=l&15, lrow4=(l>>4)*4;
  #pragma unroll
  for(int mf=0;mf<4;mf++){
    #pragma unroll
    for(int nf=0;nf<4;nf++){
      int col=col0 + 64*wc + 16*nf + lcol;
      float badd = BIAS ? (bia1[col]+bia2[col]) : 0.f;
      #pragma unroll
      for(int rr=0;rr<4;rr++){
        int row=row0 + 64*wr + 16*mf + lrow4 + rr;
        if(row<N){
          float v=acc[mf][nf][rr]+badd;
          if(OUTBF16) ((unsigned short*)Cout)[(size_t)row*DD+col]=f2b(v);
          else        ((float*)Cout)[(size_t)row*DD+col]=v;
        }
      }
    }
  }
}

// ---------------- edge logits, written in CSR (dst-sorted) order ----------------
__global__ void k_edge(const int* __restrict__ srcE, const int* __restrict__ dstE,
                       const float* __restrict__ ea, const int* __restrict__ et,
                       const int* __restrict__ epos,
                       const float* __restrict__ a_i, const float* __restrict__ a_j,
                       const float* __restrict__ v_e, const float* __restrict__ t_a,
                       float* __restrict__ alphaP, int E, int N){
  int e=blockIdx.x*blockDim.x+threadIdx.x;
  if(e>=E+N) return;
  int s,d,ty;
  float eattr[16];
  if(e<E){
    s=srcE[e]; d=dstE[e]; ty=et[e];
    float4 q0=*(const float4*)&ea[(size_t)e*16+0];
    float4 q1=*(const float4*)&ea[(size_t)e*16+4];
    float4 q2=*(const float4*)&ea[(size_t)e*16+8];
    float4 q3=*(const float4*)&ea[(size_t)e*16+12];
    eattr[0]=q0.x;eattr[1]=q0.y;eattr[2]=q0.z;eattr[3]=q0.w;
    eattr[4]=q1.x;eattr[5]=q1.y;eattr[6]=q1.z;eattr[7]=q1.w;
    eattr[8]=q2.x;eattr[9]=q2.y;eattr[10]=q2.z;eattr[11]=q2.w;
    eattr[12]=q3.x;eattr[13]=q3.y;eattr[14]=q3.z;eattr[15]=q3.w;
  }else{
    s=e-E; d=s; ty=6;
    #pragma unroll
    for(int k=0;k<16;k++) eattr[k]=1.f;
  }
  int pos=epos[e];
  const float* ai=&a_i[(size_t)d*8];
  const float* aj=&a_j[(size_t)s*8];
  #pragma unroll
  for(int h=0;h<8;h++){
    float v=ai[h]+aj[h]+t_a[ty*8+h];
    #pragma unroll
    for(int k=0;k<16;k++) v+=eattr[k]*v_e[k*8+h];
    alphaP[(size_t)pos*8+h] = (v>=0.f)? v : 0.2f*v;
  }
}

// ---------------- segment softmax + aggregation: ONE WAVE PER NODE ----------------
// lane roles: LOAD role (slot_L=l>>3, head_L=l&7) for alpha/esrc streams;
// GATHER role: lane l covers cols 4l..4l+3 (head ghead=l>>3).
// Chunk of 8 edges: 1 coalesced alpha load + 1 broadcast esrc load + 1 exp/lane,
// then 8 independent ysb-row gather chains (2 shuffles each) for max MLP.
__global__ __launch_bounds__(256) void k_agg(const int* __restrict__ row_off,
                      const int* __restrict__ esrc, const float* __restrict__ alphaP,
                      const unsigned short* __restrict__ ysb, unsigned short* __restrict__ aggb, int N){
  int wv=threadIdx.x>>6, l=threadIdx.x&63;
  int n=blockIdx.x*4+wv;
  if(n>=N) return;
  int beg=row_off[n], deg=row_off[n+1]-beg;
  int slotL=l>>3, headL=l&7;
  // pass 1: per-head max (lane layout (slot,head) matches pass 2 loads)
  float mx=-3e38f;
  for(int i=slotL;i<deg;i+=8) mx=fmaxf(mx, alphaP[(size_t)(beg+i)*8+headL]);
  mx=fmaxf(mx,__shfl_xor(mx,8));
  mx=fmaxf(mx,__shfl_xor(mx,16));
  mx=fmaxf(mx,__shfl_xor(mx,32));   // mx now = max for head headL, all lanes with that headL
  int ghead=l>>3;
  float ssum=0.f, acc0=0.f, acc1=0.f, acc2=0.f, acc3=0.f;
  for(int base=0;base<deg;base+=8){
    int i=base+slotL;
    bool ok=(i<deg);
    int ic=ok?i:(deg-1);
    float av = ok ? alphaP[(size_t)(beg+i)*8+headL] : -3e38f;
    int sv = esrc[beg+ic];
    float wvv = __expf(av-mx);       // 0 for padding lanes
    int cnt=min(8,deg-base);
    #pragma unroll
    for(int u=0;u<8;u++){
      if(u<cnt){
        float wgt=__shfl(wvv,(u<<3)|ghead);   // lane u*8+ghead holds (slot u, head ghead)
        int   si =__shfl(sv,(u<<3));          // lane u*8 holds src of slot u
        ssum+=wgt;
        ushort4 y=*(const ushort4*)&ysb[(size_t)si*DD+4*l];
        acc0+=wgt*b2f(y.x); acc1+=wgt*b2f(y.y); acc2+=wgt*b2f(y.z); acc3+=wgt*b2f(y.w);
      }
    }
  }
  float inv=1.f/(ssum+1e-16f);
  ushort4 o;
  o.x=f2b(acc0*inv); o.y=f2b(acc1*inv); o.z=f2b(acc2*inv); o.w=f2b(acc3*inv);
  *(ushort4*)&aggb[(size_t)n*DD+4*l]=o;
}

// ---------------- fused LayerNorm + residual + BN column partials ----------------
// grid = NB(256) blocks, each handles rows b, b+NB, ... ; per-row shfl reduce;
// thread tid owns column tid; per-block column partials written at the end (no atomics).
__global__ __launch_bounds__(256) void k_lnbn(const float* __restrict__ z, const float* __restrict__ xin,
                         const float* __restrict__ lg, const float* __restrict__ lb,
                         float* __restrict__ hout, float* __restrict__ psum, float* __restrict__ psq, int N){
  __shared__ float ws[2][8];
  int b=blockIdx.x, tid=threadIdx.x;
  int wv=tid>>6, ln=tid&63;
  float lgv=lg[tid], lbv=lb[tid];
  float ps=0.f, pq=0.f;
  int it=0;
  for(int r=b; r<N; r+=256, ++it){
    float v=z[(size_t)r*DD+tid];
    float s=v, q=v*v;
    #pragma unroll
    for(int off=1;off<64;off<<=1){ s+=__shfl_xor(s,off); q+=__shfl_xor(q,off); }
    int buf=it&1;
    if(ln==0){ ws[buf][wv*2]=s; ws[buf][wv*2+1]=q; }
    __syncthreads();
    float S=ws[buf][0]+ws[buf][2]+ws[buf][4]+ws[buf][6];
    float Q=ws[buf][1]+ws[buf][3]+ws[buf][5]+ws[buf][7];
    float mu=S*(1.f/DD);
    float var=Q*(1.f/DD)-mu*mu;
    float rstd=rsqrtf(var+1e-5f);
    float h=(v-mu)*rstd*lgv+lbv+xin[(size_t)r*DD+tid];
    hout[(size_t)r*DD+tid]=h;
    ps+=h; pq+=h*h;
  }
  psum[(size_t)b*DD+tid]=ps;
  psq[(size_t)b*DD+tid]=pq;
}

// ---------------- BN finalize from partials ----------------
__global__ void k_bnfin(const float* __restrict__ psum, const float* __restrict__ psq,
                        const float* __restrict__ g, const float* __restrict__ b,
                        float* scale, float* shift, int N, int NB){
  int c=threadIdx.x;
  float s=0.f,q=0.f;
  for(int bk=0;bk<NB;bk++){ s+=psum[(size_t)bk*DD+c]; q+=psq[(size_t)bk*DD+c]; }
  float inv=1.f/(float)N;
  float mu=s*inv;
  float var=q*inv - mu*mu;
  float sc=g[c]*rsqrtf(var+1e-5f);
  scale[c]=sc;
  shift[c]=b[c]-mu*sc;
}

// out = relu(h*scale + shift [+ res]); optionally also emit bf16 copy + next-layer a_i
template<bool RES, bool CVT>
__global__ __launch_bounds__(256) void k_bnapply(const float* __restrict__ hm, const float* __restrict__ scale,
                          const float* __restrict__ shift, const float* __restrict__ res,
                          float* __restrict__ outp, unsigned short* __restrict__ xb,
                          const float* __restrict__ wd_as, float* __restrict__ a_i, int N){
  __shared__ float red[DD*HH];
  __shared__ float part[8][8];
  int n=blockIdx.x, tid=threadIdx.x;
  float v=hm[(size_t)n*DD+tid]*scale[tid]+shift[tid];
  if(RES) v+=res[(size_t)n*DD+tid];
  v=fmaxf(v,0.f);
  outp[(size_t)n*DD+tid]=v;
  if(CVT){
    xb[(size_t)n*DD+tid]=f2b(v);
    #pragma unroll
    for(int h=0;h<HH;h++) red[tid*HH+h]=v*wd_as[tid*HH+h];
    __syncthreads();
    if(tid<64){
      int h=tid&7, ch=tid>>3;
      float s=0.f;
      for(int k=ch*32;k<ch*32+32;k++) s+=red[k*HH+h];
      part[ch][h]=s;
    }
    __syncthreads();
    if(tid<8){
      float s=0.f;
      #pragma unroll
      for(int ch=0;ch<8;ch++) s+=part[ch][tid];
      a_i[(size_t)n*HH+tid]=s;
    }
  }
}

extern "C" void kernel_launch(void* const* d_in, const int* in_sizes, int n_in,
                              void* d_out, int out_size, void* d_ws, size_t ws_size,
                              hipStream_t stream) {
  const float* x  = (const float*)d_in[0];
  const int*   ei = (const int*)d_in[1];
  const float* ea = (const float*)d_in[2];
  const int*   et = (const int*)d_in[3];
  int N = in_sizes[0]/DD;
  int E = in_sizes[3];
  int Etot = E+N;
  const int* srcE = ei;
  const int* dstE = ei + E;

  const float* Ws1=(const float*)d_in[4];  const float* Wd1=(const float*)d_in[5];
  const float* as1=(const float*)d_in[6];  const float* ad1=(const float*)d_in[7];
  const float* We1=(const float*)d_in[8];  const float* ae1=(const float*)d_in[9];
  const float* te1=(const float*)d_in[10]; const float* Wo1=(const float*)d_in[11];
  const float* bo1=(const float*)d_in[12]; const float* b1 =(const float*)d_in[13];
  const float* lg1=(const float*)d_in[14]; const float* lb1=(const float*)d_in[15];
  const float* Ws2=(const float*)d_in[16]; const float* Wd2=(const float*)d_in[17];
  const float* as2=(const float*)d_in[18]; const float* ad2=(const float*)d_in[19];
  const float* We2=(const float*)d_in[20]; const float* ae2=(const float*)d_in[21];
  const float* te2=(const float*)d_in[22]; const float* Wo2=(const float*)d_in[23];
  const float* bo2=(const float*)d_in[24]; const float* b2 =(const float*)d_in[25];
  const float* lg2=(const float*)d_in[26]; const float* lb2=(const float*)d_in[27];
  const float* bng1=(const float*)d_in[28]; const float* bnb1=(const float*)d_in[29];
  const float* bng2=(const float*)d_in[30]; const float* bnb2=(const float*)d_in[31];

  char* p=(char*)d_ws;
  auto alloc=[&](size_t bytes)->void*{ void* r=(void*)p; p+=(bytes+255)&~(size_t)255; return r; };
  unsigned short* xb   =(unsigned short*)alloc((size_t)N*DD*2);
  unsigned short* ysb  =(unsigned short*)alloc((size_t)N*DD*2);
  unsigned short* aggb =(unsigned short*)alloc((size_t)N*DD*2);
  float* Sreg  =(float*)alloc((size_t)N*DD*4);        // alphaP (Etot*8*4=10.9MB) then z (20.5MB)
  float* xout1 =(float*)alloc((size_t)N*DD*4);
  float* a_i   =(float*)alloc((size_t)N*HH*4);
  float* a_j   =(float*)alloc((size_t)N*HH*4);
  float* wd_as1=(float*)alloc(DD*HH*4);
  float* v_e1  =(float*)alloc(16*HH*4);
  float* t_a1  =(float*)alloc(7*HH*4);
  float* wd_as2=(float*)alloc(DD*HH*4);
  float* v_e2  =(float*)alloc(16*HH*4);
  float* t_a2  =(float*)alloc(7*HH*4);
  float* psum  =(float*)alloc(256*DD*4);
  float* psq   =(float*)alloc(256*DD*4);
  float* scl   =(float*)alloc(256*4);
  float* shf   =(float*)alloc(256*4);
  unsigned short* Wsb1T=(unsigned short*)alloc((size_t)DD*DD*2);
  unsigned short* Wob1T=(unsigned short*)alloc((size_t)DD*DD*2);
  unsigned short* Wsb2T=(unsigned short*)alloc((size_t)DD*DD*2);
  unsigned short* Wob2T=(unsigned short*)alloc((size_t)DD*DD*2);
  int* cnt     =(int*)alloc((size_t)N*4);
  int* row_off =(int*)alloc((size_t)(N+1)*4);
  int* cursor  =(int*)alloc((size_t)N*4);
  int* epos    =(int*)alloc((size_t)Etot*4);
  int* esrc    =(int*)alloc((size_t)Etot*4);
  float* hbuf  =(float*)d_out;
  float* alphaP=Sreg;
  float* zbuf=Sreg;

  dim3 gg(2,(N+127)/128);
  int aggGrid=(N+3)/4;
  const int NB=256;

  // upfront: CSR + weight prep (both layers)
  k_zero_i<<<(N+255)/256,256,0,stream>>>(cnt,N);
  k_count<<<(Etot+255)/256,256,0,stream>>>(dstE,E,N,cnt);
  k_scan<<<1,1024,0,stream>>>(cnt,N,row_off,cursor);
  k_fill<<<(Etot+255)/256,256,0,stream>>>(srcE,dstE,E,N,cursor,epos,esrc);
  k_cvt_wT<<<DD,DD,0,stream>>>(Ws1,Wsb1T);
  k_cvt_wT<<<DD,DD,0,stream>>>(Wo1,Wob1T);
  k_cvt_wT<<<DD,DD,0,stream>>>(Ws2,Wsb2T);
  k_cvt_wT<<<DD,DD,0,stream>>>(Wo2,Wob2T);
  k_pre<<<1,256,0,stream>>>(Wd1,as1,We1,ae1,te1,wd_as1,v_e1,t_a1);
  k_pre<<<1,256,0,stream>>>(Wd2,as2,We2,ae2,te2,wd_as2,v_e2,t_a2);

  // ---- layer 1 ----
  k_cvt_x<<<N,256,0,stream>>>(x,wd_as1,xb,a_i,N);
  k_gemm_mfma<true,false><<<gg,256,0,stream>>>(xb,Wsb1T,nullptr,nullptr,(void*)ysb,N);
  k_aj<<<N,256,0,stream>>>(ysb,ad1,a_j,N);
  k_edge<<<(Etot+255)/256,256,0,stream>>>(srcE,dstE,ea,et,epos,a_i,a_j,v_e1,t_a1,alphaP,E,N);
  k_agg<<<aggGrid,256,0,stream>>>(row_off,esrc,alphaP,ysb,aggb,N);
  k_gemm_mfma<false,true><<<gg,256,0,stream>>>(aggb,Wob1T,bo1,b1,(void*)zbuf,N);
  k_lnbn<<<NB,256,0,stream>>>(zbuf,x,lg1,lb1,hbuf,psum,psq,N);
  k_bnfin<<<1,256,0,stream>>>(psum,psq,bng1,bnb1,scl,shf,N,NB);
  k_bnapply<false,true><<<N,256,0,stream>>>(hbuf,scl,shf,nullptr,xout1,xb,wd_as2,a_i,N);

  // ---- layer 2 ----
  k_gemm_mfma<true,false><<<gg,256,0,stream>>>(xb,Wsb2T,nullptr,nullptr,(void*)ysb,N);
  k_aj<<<N,256,0,stream>>>(ysb,ad2,a_j,N);
  k_edge<<<(Etot+255)/256,256,0,stream>>>(srcE,dstE,ea,et,epos,a_i,a_j,v_e2,t_a2,alphaP,E,N);
  k_agg<<<aggGrid,256,0,stream>>>(row_off,esrc,alphaP,ysb,aggb,N);
  k_gemm_mfma<false,true><<<gg,256,0,stream>>>(aggb,Wob2T,bo2,b2,(void*)zbuf,N);
  k_lnbn<<<NB,256,0,stream>>>(zbuf,xout1,lg2,lb2,hbuf,psum,psq,N);
  k_bnfin<<<1,256,0,stream>>>(psum,psq,bng2,bnb2,scl,shf,N,NB);
  k_bnapply<true,false><<<N,256,0,stream>>>(hbuf,scl,shf,x,(float*)d_out,nullptr,nullptr,nullptr,N);
}

// Round 6
// 457.948 us; speedup vs baseline: 1.2819x; 1.2819x over previous
//
#include <hip/hip_runtime.h>

#define DD 256
#define HH 8
#define CC 32

typedef __attribute__((ext_vector_type(8))) short short8;
typedef __attribute__((ext_vector_type(4))) float f32x4;

static __device__ __forceinline__ unsigned short f2b(float f){
  unsigned u = __float_as_uint(f);
  u = u + 0x7FFFu + ((u >> 16) & 1u);          // RNE
  return (unsigned short)(u >> 16);
}
static __device__ __forceinline__ float b2f(unsigned short s){
  return __uint_as_float(((unsigned)s) << 16);
}

// ---------------- utility ----------------
__global__ void k_zero_i(int* p, int n){ int i=blockIdx.x*blockDim.x+threadIdx.x; if(i<n) p[i]=0; }

// ---------------- CSR build ----------------
__global__ void k_count(const int* __restrict__ dstE, int E, int N, int* cnt){
  int e=blockIdx.x*blockDim.x+threadIdx.x;
  if(e<E+N){ int d=(e<E)? dstE[e] : (e-E); atomicAdd(&cnt[d],1); }
}

__global__ __launch_bounds__(1024) void k_scan(const int* __restrict__ cnt, int N, int* row_off, int* cursor){
  __shared__ int part[1024];
  int t=threadIdx.x;
  int chunk=(N+1023)>>10;
  int s=0;
  for(int j=0;j<chunk;j++){ int i=t*chunk+j; if(i<N) s+=cnt[i]; }
  part[t]=s; __syncthreads();
  for(int off=1; off<1024; off<<=1){
    int v=(t>=off)? part[t-off]:0;
    __syncthreads();
    part[t]+=v;
    __syncthreads();
  }
  int run=(t==0)?0:part[t-1];
  for(int j=0;j<chunk;j++){ int i=t*chunk+j; if(i<N){ row_off[i]=run; cursor[i]=run; run+=cnt[i]; } }
  if(t==1023) row_off[N]=part[1023];
}

// emits e->pos mapping (epos) and CSR-ordered sources (esrc)
__global__ void k_fill(const int* __restrict__ srcE, const int* __restrict__ dstE, int E, int N,
                       int* cursor, int* epos, int* esrc){
  int e=blockIdx.x*blockDim.x+threadIdx.x;
  if(e>=E+N) return;
  int s,d;
  if(e<E){ s=srcE[e]; d=dstE[e]; } else { s=e-E; d=s; }
  int pos=atomicAdd(&cursor[d],1);
  epos[e]=pos; esrc[pos]=s;
}

// ---------------- weight transpose + bf16 convert: Wt[c][k] = W[k][c] ----------------
__global__ void k_cvt_wT(const float* __restrict__ W, unsigned short* __restrict__ Wt){
  int c=blockIdx.x, k=threadIdx.x;
  Wt[(size_t)c*DD+k] = f2b(W[(size_t)k*DD+c]);
}

// ---------------- folded logit weights ----------------
__global__ void k_pre(const float* __restrict__ Wd, const float* __restrict__ as_,
                      const float* __restrict__ We, const float* __restrict__ ae,
                      const float* __restrict__ te,
                      float* wd_as, float* v_e, float* t_a){
  int t=threadIdx.x;
  for(int idx=t; idx<DD*HH; idx+=256){
    int k=idx>>3, h=idx&7;
    const float* w=&Wd[k*DD+h*CC]; const float* a=&as_[h*CC];
    float s=0;
    #pragma unroll
    for(int c=0;c<CC;c++) s+=w[c]*a[c];
    wd_as[idx]=s;
  }
  for(int idx=t; idx<16*HH; idx+=256){
    int k=idx>>3, h=idx&7;
    const float* w=&We[k*DD+h*CC]; const float* a=&ae[h*CC];
    float s=0;
    #pragma unroll
    for(int c=0;c<CC;c++) s+=w[c]*a[c];
    v_e[idx]=s;
  }
  for(int idx=t; idx<7*HH; idx+=256){
    int k=idx>>3, h=idx&7;
    const float* w=&te[k*DD+h*CC]; const float* a=&ae[h*CC];
    float s=0;
    #pragma unroll
    for(int c=0;c<CC;c++) s+=w[c]*a[c];
    t_a[idx]=s;
  }
}

// ---------------- x -> bf16 + a_i = x @ wd_as ----------------
__global__ __launch_bounds__(256) void k_cvt_x(const float* __restrict__ xin, const float* __restrict__ wd_as,
                        unsigned short* __restrict__ xb, float* __restrict__ a_i, int N){
  __shared__ float red[DD*HH];     // [k][h] 8KB
  __shared__ float part[8][8];
  int n=blockIdx.x, tid=threadIdx.x;
  float v=xin[(size_t)n*DD+tid];
  xb[(size_t)n*DD+tid]=f2b(v);
  #pragma unroll
  for(int h=0;h<HH;h++) red[tid*HH+h]=v*wd_as[tid*HH+h];
  __syncthreads();
  if(tid<64){
    int h=tid&7, ch=tid>>3;
    float s=0.f;
    for(int k=ch*32;k<ch*32+32;k++) s+=red[k*HH+h];
    part[ch][h]=s;
  }
  __syncthreads();
  if(tid<8){
    float s=0.f;
    #pragma unroll
    for(int ch=0;ch<8;ch++) s+=part[ch][tid];
    a_i[(size_t)n*HH+tid]=s;
  }
}

// ---------------- a_j[n,h] = sum_c ys[n,32h+c]*ad[h,c] (ys bf16) ----------------
__global__ void k_aj(const unsigned short* __restrict__ ysb, const float* __restrict__ ad,
                     float* __restrict__ a_j, int N){
  int n=blockIdx.x, tid=threadIdx.x;
  float p=b2f(ysb[(size_t)n*DD+tid])*ad[tid];
  #pragma unroll
  for(int off=16;off>0;off>>=1) p+=__shfl_xor(p,off);
  if((tid&31)==0) a_j[(size_t)n*HH+(tid>>5)]=p;
}

// ---------------- bf16 MFMA GEMM: C[N,256] = A_bf16[N,256] @ B (Bt = B^T bf16) ----------------
// tile 128x128, BK=32, 4 waves; wave w -> 64x64 quadrant (wr=w>>1, wc=w&1), 4x4 MFMA frags.
// Register-prefetch software pipeline; LDS XOR-granule swizzle.
template<bool OUTBF16, bool BIAS>
__global__ __launch_bounds__(256) void k_gemm_mfma(const unsigned short* __restrict__ A,
                                                   const unsigned short* __restrict__ Bt,
                                                   const float* __restrict__ bia1, const float* __restrict__ bia2,
                                                   void* __restrict__ Cout, int N){
  __shared__ char lds[16384];   // As 128x32 (8KB) + Bs 128x32 (8KB)
  int tid=threadIdx.x;
  int w=tid>>6, l=tid&63;
  int wr=w>>1, wc=w&1;
  int row0=blockIdx.y*128, col0=blockIdx.x*128;

  int sr=tid>>2, skc=tid&3;
  int kcs=skc^((sr>>1)&3);
  int slot1=sr*4+skc, slot2=(sr+64)*4+skc;
  int gr1=row0+sr, gr2=row0+64+sr;
  size_t boff1=(size_t)(col0+sr)*DD, boff2=(size_t)(col0+64+sr)*DD;

  int x15=l&15;
  int lp=x15*64 + ((l>>4)^((x15>>1)&3))*16;

  f32x4 acc[4][4];
  #pragma unroll
  for(int i=0;i<4;i++)
    #pragma unroll
    for(int jj=0;jj<4;jj++) acc[i][jj]=(f32x4)0.f;

  const short8 zero8=(short8)0;
  short8 av1,av2,bv1,bv2;
  av1 = (gr1<N) ? *(const short8*)&A[(size_t)gr1*DD + kcs*8] : zero8;
  av2 = (gr2<N) ? *(const short8*)&A[(size_t)gr2*DD + kcs*8] : zero8;
  bv1 = *(const short8*)&Bt[boff1 + kcs*8];
  bv2 = *(const short8*)&Bt[boff2 + kcs*8];

  for(int kt=0;kt<DD;kt+=32){
    __syncthreads();
    *(short8*)(lds + slot1*16) = av1;
    *(short8*)(lds + slot2*16) = av2;
    *(short8*)(lds + 8192 + slot1*16) = bv1;
    *(short8*)(lds + 8192 + slot2*16) = bv2;
    __syncthreads();
    if(kt+32<DD){
      int ko=kt+32+kcs*8;
      av1 = (gr1<N) ? *(const short8*)&A[(size_t)gr1*DD + ko] : zero8;
      av2 = (gr2<N) ? *(const short8*)&A[(size_t)gr2*DD + ko] : zero8;
      bv1 = *(const short8*)&Bt[boff1 + ko];
      bv2 = *(const short8*)&Bt[boff2 + ko];
    }
    short8 af[4], bf[4];
    #pragma unroll
    for(int mf=0;mf<4;mf++) af[mf]=*(short8*)(lds + (64*wr+16*mf)*64 + lp);
    #pragma unroll
    for(int nf=0;nf<4;nf++) bf[nf]=*(short8*)(lds + 8192 + (64*wc+16*nf)*64 + lp);
    #pragma unroll
    for(int mf=0;mf<4;mf++)
      #pragma unroll
      for(int nf=0;nf<4;nf++)
        acc[mf][nf]=__builtin_amdgcn_mfma_f32_16x16x32_bf16(af[mf],bf[nf],acc[mf][nf],0,0,0);
  }

  int lcol=l&15, lrow4=(l>>4)*4;
  #pragma unroll
  for(int mf=0;mf<4;mf++){
    #pragma unroll
    for(int nf=0;nf<4;nf++){
      int col=col0 + 64*wc + 16*nf + lcol;
      float badd = BIAS ? (bia1[col]+bia2[col]) : 0.f;
      #pragma unroll
      for(int rr=0;rr<4;rr++){
        int row=row0 + 64*wr + 16*mf + lrow4 + rr;
        if(row<N){
          float v=acc[mf][nf][rr]+badd;
          if(OUTBF16) ((unsigned short*)Cout)[(size_t)row*DD+col]=f2b(v);
          else        ((float*)Cout)[(size_t)row*DD+col]=v;
        }
      }
    }
  }
}

// ---------------- edge logits, written in CSR (dst-sorted) order ----------------
__global__ void k_edge(const int* __restrict__ srcE, const int* __restrict__ dstE,
                       const float* __restrict__ ea, const int* __restrict__ et,
                       const int* __restrict__ epos,
                       const float* __restrict__ a_i, const float* __restrict__ a_j,
                       const float* __restrict__ v_e, const float* __restrict__ t_a,
                       float* __restrict__ alphaP, int E, int N){
  int e=blockIdx.x*blockDim.x+threadIdx.x;
  if(e>=E+N) return;
  int s,d,ty;
  float eattr[16];
  if(e<E){
    s=srcE[e]; d=dstE[e]; ty=et[e];
    float4 q0=*(const float4*)&ea[(size_t)e*16+0];
    float4 q1=*(const float4*)&ea[(size_t)e*16+4];
    float4 q2=*(const float4*)&ea[(size_t)e*16+8];
    float4 q3=*(const float4*)&ea[(size_t)e*16+12];
    eattr[0]=q0.x;eattr[1]=q0.y;eattr[2]=q0.z;eattr[3]=q0.w;
    eattr[4]=q1.x;eattr[5]=q1.y;eattr[6]=q1.z;eattr[7]=q1.w;
    eattr[8]=q2.x;eattr[9]=q2.y;eattr[10]=q2.z;eattr[11]=q2.w;
    eattr[12]=q3.x;eattr[13]=q3.y;eattr[14]=q3.z;eattr[15]=q3.w;
  }else{
    s=e-E; d=s; ty=6;
    #pragma unroll
    for(int k=0;k<16;k++) eattr[k]=1.f;
  }
  int pos=epos[e];
  const float* ai=&a_i[(size_t)d*8];
  const float* aj=&a_j[(size_t)s*8];
  #pragma unroll
  for(int h=0;h<8;h++){
    float v=ai[h]+aj[h]+t_a[ty*8+h];
    #pragma unroll
    for(int k=0;k<16;k++) v+=eattr[k]*v_e[k*8+h];
    alphaP[(size_t)pos*8+h] = (v>=0.f)? v : 0.2f*v;
  }
}

// ---------------- segment softmax + aggregation: ONE WAVE PER NODE ----------------
__global__ __launch_bounds__(256) void k_agg(const int* __restrict__ row_off,
                      const int* __restrict__ esrc, const float* __restrict__ alphaP,
                      const unsigned short* __restrict__ ysb, unsigned short* __restrict__ aggb, int N){
  int wv=threadIdx.x>>6, l=threadIdx.x&63;
  int n=blockIdx.x*4+wv;
  if(n>=N) return;
  int beg=row_off[n], deg=row_off[n+1]-beg;
  int slotL=l>>3, headL=l&7;
  float mx=-3e38f;
  for(int i=slotL;i<deg;i+=8) mx=fmaxf(mx, alphaP[(size_t)(beg+i)*8+headL]);
  mx=fmaxf(mx,__shfl_xor(mx,8));
  mx=fmaxf(mx,__shfl_xor(mx,16));
  mx=fmaxf(mx,__shfl_xor(mx,32));
  int ghead=l>>3;
  float ssum=0.f, acc0=0.f, acc1=0.f, acc2=0.f, acc3=0.f;
  for(int base=0;base<deg;base+=8){
    int i=base+slotL;
    bool ok=(i<deg);
    int ic=ok?i:(deg-1);
    float av = ok ? alphaP[(size_t)(beg+i)*8+headL] : -3e38f;
    int sv = esrc[beg+ic];
    float wvv = __expf(av-mx);
    int cnt=min(8,deg-base);
    #pragma unroll
    for(int u=0;u<8;u++){
      if(u<cnt){
        float wgt=__shfl(wvv,(u<<3)|ghead);
        int   si =__shfl(sv,(u<<3));
        ssum+=wgt;
        ushort4 y=*(const ushort4*)&ysb[(size_t)si*DD+4*l];
        acc0+=wgt*b2f(y.x); acc1+=wgt*b2f(y.y); acc2+=wgt*b2f(y.z); acc3+=wgt*b2f(y.w);
      }
    }
  }
  float inv=1.f/(ssum+1e-16f);
  ushort4 o;
  o.x=f2b(acc0*inv); o.y=f2b(acc1*inv); o.z=f2b(acc2*inv); o.w=f2b(acc3*inv);
  *(ushort4*)&aggb[(size_t)n*DD+4*l]=o;
}

// ---------------- fused LayerNorm + residual + BN column partials ----------------
__global__ __launch_bounds__(256) void k_lnbn(const float* __restrict__ z, const float* __restrict__ xin,
                         const float* __restrict__ lg, const float* __restrict__ lb,
                         float* __restrict__ hout, float* __restrict__ psum, float* __restrict__ psq, int N){
  __shared__ float ws[2][8];
  int b=blockIdx.x, tid=threadIdx.x;
  int wv=tid>>6, ln=tid&63;
  float lgv=lg[tid], lbv=lb[tid];
  float ps=0.f, pq=0.f;
  int it=0;
  for(int r=b; r<N; r+=256, ++it){
    float v=z[(size_t)r*DD+tid];
    float s=v, q=v*v;
    #pragma unroll
    for(int off=1;off<64;off<<=1){ s+=__shfl_xor(s,off); q+=__shfl_xor(q,off); }
    int buf=it&1;
    if(ln==0){ ws[buf][wv*2]=s; ws[buf][wv*2+1]=q; }
    __syncthreads();
    float S=ws[buf][0]+ws[buf][2]+ws[buf][4]+ws[buf][6];
    float Q=ws[buf][1]+ws[buf][3]+ws[buf][5]+ws[buf][7];
    float mu=S*(1.f/DD);
    float var=Q*(1.f/DD)-mu*mu;
    float rstd=rsqrtf(var+1e-5f);
    float h=(v-mu)*rstd*lgv+lbv+xin[(size_t)r*DD+tid];
    hout[(size_t)r*DD+tid]=h;
    ps+=h; pq+=h*h;
  }
  psum[(size_t)b*DD+tid]=ps;
  psq[(size_t)b*DD+tid]=pq;
}

// ---------------- BN finalize from partials: one block PER COLUMN ----------------
// block c: thread t reads psum[t*DD+c] (parallel line reads across 256 CUs), LDS-tree reduce.
__global__ __launch_bounds__(256) void k_bnfin(const float* __restrict__ psum, const float* __restrict__ psq,
                        const float* __restrict__ g, const float* __restrict__ b,
                        float* scale, float* shift, int N){
  __shared__ float rs[256], rq[256];
  int c=blockIdx.x, tid=threadIdx.x;
  rs[tid]=psum[(size_t)tid*DD+c];
  rq[tid]=psq[(size_t)tid*DD+c];
  __syncthreads();
  #pragma unroll
  for(int off=128;off>0;off>>=1){
    if(tid<off){ rs[tid]+=rs[tid+off]; rq[tid]+=rq[tid+off]; }
    __syncthreads();
  }
  if(tid==0){
    float inv=1.f/(float)N;
    float mu=rs[0]*inv;
    float var=rq[0]*inv - mu*mu;
    float sc=g[c]*rsqrtf(var+1e-5f);
    scale[c]=sc;
    shift[c]=b[c]-mu*sc;
  }
}

// out = relu(h*scale + shift [+ res]); optionally also emit bf16 copy + next-layer a_i
template<bool RES, bool CVT>
__global__ __launch_bounds__(256) void k_bnapply(const float* __restrict__ hm, const float* __restrict__ scale,
                          const float* __restrict__ shift, const float* __restrict__ res,
                          float* __restrict__ outp, unsigned short* __restrict__ xb,
                          const float* __restrict__ wd_as, float* __restrict__ a_i, int N){
  __shared__ float red[DD*HH];
  __shared__ float part[8][8];
  int n=blockIdx.x, tid=threadIdx.x;
  float v=hm[(size_t)n*DD+tid]*scale[tid]+shift[tid];
  if(RES) v+=res[(size_t)n*DD+tid];
  v=fmaxf(v,0.f);
  outp[(size_t)n*DD+tid]=v;
  if(CVT){
    xb[(size_t)n*DD+tid]=f2b(v);
    #pragma unroll
    for(int h=0;h<HH;h++) red[tid*HH+h]=v*wd_as[tid*HH+h];
    __syncthreads();
    if(tid<64){
      int h=tid&7, ch=tid>>3;
      float s=0.f;
      for(int k=ch*32;k<ch*32+32;k++) s+=red[k*HH+h];
      part[ch][h]=s;
    }
    __syncthreads();
    if(tid<8){
      float s=0.f;
      #pragma unroll
      for(int ch=0;ch<8;ch++) s+=part[ch][tid];
      a_i[(size_t)n*HH+tid]=s;
    }
  }
}

extern "C" void kernel_launch(void* const* d_in, const int* in_sizes, int n_in,
                              void* d_out, int out_size, void* d_ws, size_t ws_size,
                              hipStream_t stream) {
  const float* x  = (const float*)d_in[0];
  const int*   ei = (const int*)d_in[1];
  const float* ea = (const float*)d_in[2];
  const int*   et = (const int*)d_in[3];
  int N = in_sizes[0]/DD;
  int E = in_sizes[3];
  int Etot = E+N;
  const int* srcE = ei;
  const int* dstE = ei + E;

  const float* Ws1=(const float*)d_in[4];  const float* Wd1=(const float*)d_in[5];
  const float* as1=(const float*)d_in[6];  const float* ad1=(const float*)d_in[7];
  const float* We1=(const float*)d_in[8];  const float* ae1=(const float*)d_in[9];
  const float* te1=(const float*)d_in[10]; const float* Wo1=(const float*)d_in[11];
  const float* bo1=(const float*)d_in[12]; const float* b1 =(const float*)d_in[13];
  const float* lg1=(const float*)d_in[14]; const float* lb1=(const float*)d_in[15];
  const float* Ws2=(const float*)d_in[16]; const float* Wd2=(const float*)d_in[17];
  const float* as2=(const float*)d_in[18]; const float* ad2=(const float*)d_in[19];
  const float* We2=(const float*)d_in[20]; const float* ae2=(const float*)d_in[21];
  const float* te2=(const float*)d_in[22]; const float* Wo2=(const float*)d_in[23];
  const float* bo2=(const float*)d_in[24]; const float* b2 =(const float*)d_in[25];
  const float* lg2=(const float*)d_in[26]; const float* lb2=(const float*)d_in[27];
  const float* bng1=(const float*)d_in[28]; const float* bnb1=(const float*)d_in[29];
  const float* bng2=(const float*)d_in[30]; const float* bnb2=(const float*)d_in[31];

  char* p=(char*)d_ws;
  auto alloc=[&](size_t bytes)->void*{ void* r=(void*)p; p+=(bytes+255)&~(size_t)255; return r; };
  unsigned short* xb   =(unsigned short*)alloc((size_t)N*DD*2);
  unsigned short* ysb  =(unsigned short*)alloc((size_t)N*DD*2);
  unsigned short* aggb =(unsigned short*)alloc((size_t)N*DD*2);
  float* Sreg  =(float*)alloc((size_t)N*DD*4);        // alphaP (Etot*8*4=10.9MB) then z (20.5MB)
  float* xout1 =(float*)alloc((size_t)N*DD*4);
  float* a_i   =(float*)alloc((size_t)N*HH*4);
  float* a_j   =(float*)alloc((size_t)N*HH*4);
  float* wd_as1=(float*)alloc(DD*HH*4);
  float* v_e1  =(float*)alloc(16*HH*4);
  float* t_a1  =(float*)alloc(7*HH*4);
  float* wd_as2=(float*)alloc(DD*HH*4);
  float* v_e2  =(float*)alloc(16*HH*4);
  float* t_a2  =(float*)alloc(7*HH*4);
  float* psum  =(float*)alloc(256*DD*4);
  float* psq   =(float*)alloc(256*DD*4);
  float* scl   =(float*)alloc(256*4);
  float* shf   =(float*)alloc(256*4);
  unsigned short* Wsb1T=(unsigned short*)alloc((size_t)DD*DD*2);
  unsigned short* Wob1T=(unsigned short*)alloc((size_t)DD*DD*2);
  unsigned short* Wsb2T=(unsigned short*)alloc((size_t)DD*DD*2);
  unsigned short* Wob2T=(unsigned short*)alloc((size_t)DD*DD*2);
  int* cnt     =(int*)alloc((size_t)N*4);
  int* row_off =(int*)alloc((size_t)(N+1)*4);
  int* cursor  =(int*)alloc((size_t)N*4);
  int* epos    =(int*)alloc((size_t)Etot*4);
  int* esrc    =(int*)alloc((size_t)Etot*4);
  float* hbuf  =(float*)d_out;
  float* alphaP=Sreg;
  float* zbuf=Sreg;

  dim3 gg(2,(N+127)/128);
  int aggGrid=(N+3)/4;
  const int NB=256;

  // upfront: CSR + weight prep (both layers)
  k_zero_i<<<(N+255)/256,256,0,stream>>>(cnt,N);
  k_count<<<(Etot+255)/256,256,0,stream>>>(dstE,E,N,cnt);
  k_scan<<<1,1024,0,stream>>>(cnt,N,row_off,cursor);
  k_fill<<<(Etot+255)/256,256,0,stream>>>(srcE,dstE,E,N,cursor,epos,esrc);
  k_cvt_wT<<<DD,DD,0,stream>>>(Ws1,Wsb1T);
  k_cvt_wT<<<DD,DD,0,stream>>>(Wo1,Wob1T);
  k_cvt_wT<<<DD,DD,0,stream>>>(Ws2,Wsb2T);
  k_cvt_wT<<<DD,DD,0,stream>>>(Wo2,Wob2T);
  k_pre<<<1,256,0,stream>>>(Wd1,as1,We1,ae1,te1,wd_as1,v_e1,t_a1);
  k_pre<<<1,256,0,stream>>>(Wd2,as2,We2,ae2,te2,wd_as2,v_e2,t_a2);

  // ---- layer 1 ----
  k_cvt_x<<<N,256,0,stream>>>(x,wd_as1,xb,a_i,N);
  k_gemm_mfma<true,false><<<gg,256,0,stream>>>(xb,Wsb1T,nullptr,nullptr,(void*)ysb,N);
  k_aj<<<N,256,0,stream>>>(ysb,ad1,a_j,N);
  k_edge<<<(Etot+255)/256,256,0,stream>>>(srcE,dstE,ea,et,epos,a_i,a_j,v_e1,t_a1,alphaP,E,N);
  k_agg<<<aggGrid,256,0,stream>>>(row_off,esrc,alphaP,ysb,aggb,N);
  k_gemm_mfma<false,true><<<gg,256,0,stream>>>(aggb,Wob1T,bo1,b1,(void*)zbuf,N);
  k_lnbn<<<NB,256,0,stream>>>(zbuf,x,lg1,lb1,hbuf,psum,psq,N);
  k_bnfin<<<DD,256,0,stream>>>(psum,psq,bng1,bnb1,scl,shf,N);
  k_bnapply<false,true><<<N,256,0,stream>>>(hbuf,scl,shf,nullptr,xout1,xb,wd_as2,a_i,N);

  // ---- layer 2 ----
  k_gemm_mfma<true,false><<<gg,256,0,stream>>>(xb,Wsb2T,nullptr,nullptr,(void*)ysb,N);
  k_aj<<<N,256,0,stream>>>(ysb,ad2,a_j,N);
  k_edge<<<(Etot+255)/256,256,0,stream>>>(srcE,dstE,ea,et,epos,a_i,a_j,v_e2,t_a2,alphaP,E,N);
  k_agg<<<aggGrid,256,0,stream>>>(row_off,esrc,alphaP,ysb,aggb,N);
  k_gemm_mfma<false,true><<<gg,256,0,stream>>>(aggb,Wob2T,bo2,b2,(void*)zbuf,N);
  k_lnbn<<<NB,256,0,stream>>>(zbuf,xout1,lg2,lb2,hbuf,psum,psq,N);
  k_bnfin<<<DD,256,0,stream>>>(psum,psq,bng2,bnb2,scl,shf,N);
  k_bnapply<true,false><<<N,256,0,stream>>>(hbuf,scl,shf,x,(float*)d_out,nullptr,nullptr,nullptr,N);
}

// Round 7
// 367.036 us; speedup vs baseline: 1.5994x; 1.2477x over previous
//
#include <hip/hip_runtime.h>

#define DD 256
#define HH 8
#define CC 32

typedef __attribute__((ext_vector_type(8))) short short8;
typedef __attribute__((ext_vector_type(4))) float f32x4;

static __device__ __forceinline__ unsigned short f2b(float f){
  unsigned u = __float_as_uint(f);
  u = u + 0x7FFFu + ((u >> 16) & 1u);          // RNE
  return (unsigned short)(u >> 16);
}
static __device__ __forceinline__ float b2f(unsigned short s){
  return __uint_as_float(((unsigned)s) << 16);
}

// ---------------- utility ----------------
__global__ void k_zero_i(int* p, int n){ int i=blockIdx.x*blockDim.x+threadIdx.x; if(i<n) p[i]=0; }

// ---------------- CSR build ----------------
__global__ void k_count(const int* __restrict__ dstE, int E, int N, int* cnt){
  int e=blockIdx.x*blockDim.x+threadIdx.x;
  if(e<E+N){ int d=(e<E)? dstE[e] : (e-E); atomicAdd(&cnt[d],1); }
}

__global__ __launch_bounds__(1024) void k_scan(const int* __restrict__ cnt, int N, int* row_off, int* cursor){
  __shared__ int part[1024];
  int t=threadIdx.x;
  int chunk=(N+1023)>>10;
  int s=0;
  for(int j=0;j<chunk;j++){ int i=t*chunk+j; if(i<N) s+=cnt[i]; }
  part[t]=s; __syncthreads();
  for(int off=1; off<1024; off<<=1){
    int v=(t>=off)? part[t-off]:0;
    __syncthreads();
    part[t]+=v;
    __syncthreads();
  }
  int run=(t==0)?0:part[t-1];
  for(int j=0;j<chunk;j++){ int i=t*chunk+j; if(i<N){ row_off[i]=run; cursor[i]=run; run+=cnt[i]; } }
  if(t==1023) row_off[N]=part[1023];
}

// emits e->pos mapping (epos) and CSR-ordered sources (esrc)
__global__ void k_fill(const int* __restrict__ srcE, const int* __restrict__ dstE, int E, int N,
                       int* cursor, int* epos, int* esrc){
  int e=blockIdx.x*blockDim.x+threadIdx.x;
  if(e>=E+N) return;
  int s,d;
  if(e<E){ s=srcE[e]; d=dstE[e]; } else { s=e-E; d=s; }
  int pos=atomicAdd(&cursor[d],1);
  epos[e]=pos; esrc[pos]=s;
}

// ---------------- weight transpose + bf16 convert: Wt[c][k] = W[k][c] ----------------
__global__ void k_cvt_wT(const float* __restrict__ W, unsigned short* __restrict__ Wt){
  int c=blockIdx.x, k=threadIdx.x;
  Wt[(size_t)c*DD+k] = f2b(W[(size_t)k*DD+c]);
}

// ---------------- folded logit weights ----------------
__global__ void k_pre(const float* __restrict__ Wd, const float* __restrict__ as_,
                      const float* __restrict__ We, const float* __restrict__ ae,
                      const float* __restrict__ te,
                      float* wd_as, float* v_e, float* t_a){
  int t=threadIdx.x;
  for(int idx=t; idx<DD*HH; idx+=256){
    int k=idx>>3, h=idx&7;
    const float* w=&Wd[k*DD+h*CC]; const float* a=&as_[h*CC];
    float s=0;
    #pragma unroll
    for(int c=0;c<CC;c++) s+=w[c]*a[c];
    wd_as[idx]=s;
  }
  for(int idx=t; idx<16*HH; idx+=256){
    int k=idx>>3, h=idx&7;
    const float* w=&We[k*DD+h*CC]; const float* a=&ae[h*CC];
    float s=0;
    #pragma unroll
    for(int c=0;c<CC;c++) s+=w[c]*a[c];
    v_e[idx]=s;
  }
  for(int idx=t; idx<7*HH; idx+=256){
    int k=idx>>3, h=idx&7;
    const float* w=&te[k*DD+h*CC]; const float* a=&ae[h*CC];
    float s=0;
    #pragma unroll
    for(int c=0;c<CC;c++) s+=w[c]*a[c];
    t_a[idx]=s;
  }
}

// ---------------- x -> bf16 + a_i = x @ wd_as ----------------
__global__ __launch_bounds__(256) void k_cvt_x(const float* __restrict__ xin, const float* __restrict__ wd_as,
                        unsigned short* __restrict__ xb, float* __restrict__ a_i, int N){
  __shared__ float red[DD*HH];     // [k][h] 8KB
  __shared__ float part[8][8];
  int n=blockIdx.x, tid=threadIdx.x;
  float v=xin[(size_t)n*DD+tid];
  xb[(size_t)n*DD+tid]=f2b(v);
  #pragma unroll
  for(int h=0;h<HH;h++) red[tid*HH+h]=v*wd_as[tid*HH+h];
  __syncthreads();
  if(tid<64){
    int h=tid&7, ch=tid>>3;
    float s=0.f;
    for(int k=ch*32;k<ch*32+32;k++) s+=red[k*HH+h];
    part[ch][h]=s;
  }
  __syncthreads();
  if(tid<8){
    float s=0.f;
    #pragma unroll
    for(int ch=0;ch<8;ch++) s+=part[ch][tid];
    a_i[(size_t)n*HH+tid]=s;
  }
}

// ---------------- a_j[n,h] = sum_c ys[n,32h+c]*ad[h,c] (ys bf16) ----------------
__global__ void k_aj(const unsigned short* __restrict__ ysb, const float* __restrict__ ad,
                     float* __restrict__ a_j, int N){
  int n=blockIdx.x, tid=threadIdx.x;
  float p=b2f(ysb[(size_t)n*DD+tid])*ad[tid];
  #pragma unroll
  for(int off=16;off>0;off>>=1) p+=__shfl_xor(p,off);
  if((tid&31)==0) a_j[(size_t)n*HH+(tid>>5)]=p;
}

// ---------------- bf16 MFMA GEMM: C[N,256] = A_bf16[N,256] @ B (Bt = B^T bf16) ----------------
// tile 128x128, BK=32, 4 waves; wave w -> 64x64 quadrant (wr=w>>1, wc=w&1), 4x4 MFMA frags.
// Register-prefetch software pipeline; LDS XOR-granule swizzle.
template<bool OUTBF16, bool BIAS>
__global__ __launch_bounds__(256) void k_gemm_mfma(const unsigned short* __restrict__ A,
                                                   const unsigned short* __restrict__ Bt,
                                                   const float* __restrict__ bia1, const float* __restrict__ bia2,
                                                   void* __restrict__ Cout, int N){
  __shared__ char lds[16384];   // As 128x32 (8KB) + Bs 128x32 (8KB)
  int tid=threadIdx.x;
  int w=tid>>6, l=tid&63;
  int wr=w>>1, wc=w&1;
  int row0=blockIdx.y*128, col0=blockIdx.x*128;

  int sr=tid>>2, skc=tid&3;
  int kcs=skc^((sr>>1)&3);
  int slot1=sr*4+skc, slot2=(sr+64)*4+skc;
  int gr1=row0+sr, gr2=row0+64+sr;
  size_t boff1=(size_t)(col0+sr)*DD, boff2=(size_t)(col0+64+sr)*DD;

  int x15=l&15;
  int lp=x15*64 + ((l>>4)^((x15>>1)&3))*16;

  f32x4 acc[4][4];
  #pragma unroll
  for(int i=0;i<4;i++)
    #pragma unroll
    for(int jj=0;jj<4;jj++) acc[i][jj]=(f32x4)0.f;

  const short8 zero8=(short8)0;
  short8 av1,av2,bv1,bv2;
  av1 = (gr1<N) ? *(const short8*)&A[(size_t)gr1*DD + kcs*8] : zero8;
  av2 = (gr2<N) ? *(const short8*)&A[(size_t)gr2*DD + kcs*8] : zero8;
  bv1 = *(const short8*)&Bt[boff1 + kcs*8];
  bv2 = *(const short8*)&Bt[boff2 + kcs*8];

  for(int kt=0;kt<DD;kt+=32){
    __syncthreads();
    *(short8*)(lds + slot1*16) = av1;
    *(short8*)(lds + slot2*16) = av2;
    *(short8*)(lds + 8192 + slot1*16) = bv1;
    *(short8*)(lds + 8192 + slot2*16) = bv2;
    __syncthreads();
    if(kt+32<DD){
      int ko=kt+32+kcs*8;
      av1 = (gr1<N) ? *(const short8*)&A[(size_t)gr1*DD + ko] : zero8;
      av2 = (gr2<N) ? *(const short8*)&A[(size_t)gr2*DD + ko] : zero8;
      bv1 = *(const short8*)&Bt[boff1 + ko];
      bv2 = *(const short8*)&Bt[boff2 + ko];
    }
    short8 af[4], bf[4];
    #pragma unroll
    for(int mf=0;mf<4;mf++) af[mf]=*(short8*)(lds + (64*wr+16*mf)*64 + lp);
    #pragma unroll
    for(int nf=0;nf<4;nf++) bf[nf]=*(short8*)(lds + 8192 + (64*wc+16*nf)*64 + lp);
    #pragma unroll
    for(int mf=0;mf<4;mf++)
      #pragma unroll
      for(int nf=0;nf<4;nf++)
        acc[mf][nf]=__builtin_amdgcn_mfma_f32_16x16x32_bf16(af[mf],bf[nf],acc[mf][nf],0,0,0);
  }

  int lcol=l&15, lrow4=(l>>4)*4;
  #pragma unroll
  for(int mf=0;mf<4;mf++){
    #pragma unroll
    for(int nf=0;nf<4;nf++){
      int col=col0 + 64*wc + 16*nf + lcol;
      float badd = BIAS ? (bia1[col]+bia2[col]) : 0.f;
      #pragma unroll
      for(int rr=0;rr<4;rr++){
        int row=row0 + 64*wr + 16*mf + lrow4 + rr;
        if(row<N){
          float v=acc[mf][nf][rr]+badd;
          if(OUTBF16) ((unsigned short*)Cout)[(size_t)row*DD+col]=f2b(v);
          else        ((float*)Cout)[(size_t)row*DD+col]=v;
        }
      }
    }
  }
}

// ---------------- edge logits, written in CSR (dst-sorted) order ----------------
__global__ void k_edge(const int* __restrict__ srcE, const int* __restrict__ dstE,
                       const float* __restrict__ ea, const int* __restrict__ et,
                       const int* __restrict__ epos,
                       const float* __restrict__ a_i, const float* __restrict__ a_j,
                       const float* __restrict__ v_e, const float* __restrict__ t_a,
                       float* __restrict__ alphaP, int E, int N){
  int e=blockIdx.x*blockDim.x+threadIdx.x;
  if(e>=E+N) return;
  int s,d,ty;
  float eattr[16];
  if(e<E){
    s=srcE[e]; d=dstE[e]; ty=et[e];
    float4 q0=*(const float4*)&ea[(size_t)e*16+0];
    float4 q1=*(const float4*)&ea[(size_t)e*16+4];
    float4 q2=*(const float4*)&ea[(size_t)e*16+8];
    float4 q3=*(const float4*)&ea[(size_t)e*16+12];
    eattr[0]=q0.x;eattr[1]=q0.y;eattr[2]=q0.z;eattr[3]=q0.w;
    eattr[4]=q1.x;eattr[5]=q1.y;eattr[6]=q1.z;eattr[7]=q1.w;
    eattr[8]=q2.x;eattr[9]=q2.y;eattr[10]=q2.z;eattr[11]=q2.w;
    eattr[12]=q3.x;eattr[13]=q3.y;eattr[14]=q3.z;eattr[15]=q3.w;
  }else{
    s=e-E; d=s; ty=6;
    #pragma unroll
    for(int k=0;k<16;k++) eattr[k]=1.f;
  }
  int pos=epos[e];
  const float* ai=&a_i[(size_t)d*8];
  const float* aj=&a_j[(size_t)s*8];
  #pragma unroll
  for(int h=0;h<8;h++){
    float v=ai[h]+aj[h]+t_a[ty*8+h];
    #pragma unroll
    for(int k=0;k<16;k++) v+=eattr[k]*v_e[k*8+h];
    alphaP[(size_t)pos*8+h] = (v>=0.f)? v : 0.2f*v;
  }
}

// ---------------- segment softmax + aggregation: ONE WAVE PER NODE ----------------
__global__ __launch_bounds__(256) void k_agg(const int* __restrict__ row_off,
                      const int* __restrict__ esrc, const float* __restrict__ alphaP,
                      const unsigned short* __restrict__ ysb, unsigned short* __restrict__ aggb, int N){
  int wv=threadIdx.x>>6, l=threadIdx.x&63;
  int n=blockIdx.x*4+wv;
  if(n>=N) return;
  int beg=row_off[n], deg=row_off[n+1]-beg;
  int slotL=l>>3, headL=l&7;
  float mx=-3e38f;
  for(int i=slotL;i<deg;i+=8) mx=fmaxf(mx, alphaP[(size_t)(beg+i)*8+headL]);
  mx=fmaxf(mx,__shfl_xor(mx,8));
  mx=fmaxf(mx,__shfl_xor(mx,16));
  mx=fmaxf(mx,__shfl_xor(mx,32));
  int ghead=l>>3;
  float ssum=0.f, acc0=0.f, acc1=0.f, acc2=0.f, acc3=0.f;
  for(int base=0;base<deg;base+=8){
    int i=base+slotL;
    bool ok=(i<deg);
    int ic=ok?i:(deg-1);
    float av = ok ? alphaP[(size_t)(beg+i)*8+headL] : -3e38f;
    int sv = esrc[beg+ic];
    float wvv = __expf(av-mx);
    int cnt=min(8,deg-base);
    #pragma unroll
    for(int u=0;u<8;u++){
      if(u<cnt){
        float wgt=__shfl(wvv,(u<<3)|ghead);
        int   si =__shfl(sv,(u<<3));
        ssum+=wgt;
        ushort4 y=*(const ushort4*)&ysb[(size_t)si*DD+4*l];
        acc0+=wgt*b2f(y.x); acc1+=wgt*b2f(y.y); acc2+=wgt*b2f(y.z); acc3+=wgt*b2f(y.w);
      }
    }
  }
  float inv=1.f/(ssum+1e-16f);
  ushort4 o;
  o.x=f2b(acc0*inv); o.y=f2b(acc1*inv); o.z=f2b(acc2*inv); o.w=f2b(acc3*inv);
  *(ushort4*)&aggb[(size_t)n*DD+4*l]=o;
}

// ---------------- fused LayerNorm + residual + BN column partials ----------------
// 512 blocks x 4 waves; wave g=b*4+wv handles rows g, g+2048, ... ; lane l owns cols 4l..4l+3.
// No __syncthreads in the row loop (wave-level shfl reduce); one LDS combine at the end.
#define NB_LN 512
__global__ __launch_bounds__(256) void k_lnbn(const float* __restrict__ z, const float* __restrict__ xin,
                         const float* __restrict__ lg, const float* __restrict__ lb,
                         float* __restrict__ hout, float* __restrict__ psum, float* __restrict__ psq, int N){
  __shared__ float sps[4][DD], spq[4][DD];
  int b=blockIdx.x, tid=threadIdx.x, wv=tid>>6, l=tid&63;
  int c0=4*l;
  float4 lgv=*(const float4*)&lg[c0];
  float4 lbv=*(const float4*)&lb[c0];
  float ps0=0.f,ps1=0.f,ps2=0.f,ps3=0.f,pq0=0.f,pq1=0.f,pq2=0.f,pq3=0.f;
  for(int r=b*4+wv; r<N; r+=NB_LN*4){
    float4 v=*(const float4*)&z[(size_t)r*DD+c0];
    float s=v.x+v.y+v.z+v.w;
    float q=v.x*v.x+v.y*v.y+v.z*v.z+v.w*v.w;
    #pragma unroll
    for(int off=1;off<64;off<<=1){ s+=__shfl_xor(s,off); q+=__shfl_xor(q,off); }
    float mu=s*(1.f/DD);
    float var=q*(1.f/DD)-mu*mu;
    float rstd=rsqrtf(var+1e-5f);
    float4 xr=*(const float4*)&xin[(size_t)r*DD+c0];
    float4 h;
    h.x=(v.x-mu)*rstd*lgv.x+lbv.x+xr.x;
    h.y=(v.y-mu)*rstd*lgv.y+lbv.y+xr.y;
    h.z=(v.z-mu)*rstd*lgv.z+lbv.z+xr.z;
    h.w=(v.w-mu)*rstd*lgv.w+lbv.w+xr.w;
    *(float4*)&hout[(size_t)r*DD+c0]=h;
    ps0+=h.x;ps1+=h.y;ps2+=h.z;ps3+=h.w;
    pq0+=h.x*h.x;pq1+=h.y*h.y;pq2+=h.z*h.z;pq3+=h.w*h.w;
  }
  sps[wv][c0+0]=ps0; sps[wv][c0+1]=ps1; sps[wv][c0+2]=ps2; sps[wv][c0+3]=ps3;
  spq[wv][c0+0]=pq0; spq[wv][c0+1]=pq1; spq[wv][c0+2]=pq2; spq[wv][c0+3]=pq3;
  __syncthreads();
  float s=sps[0][tid]+sps[1][tid]+sps[2][tid]+sps[3][tid];
  float q=spq[0][tid]+spq[1][tid]+spq[2][tid]+spq[3][tid];
  psum[(size_t)b*DD+tid]=s;
  psq[(size_t)b*DD+tid]=q;
}

// ---------------- BN finalize from partials: one block PER COLUMN (NB_LN=512 partials) ----------------
__global__ __launch_bounds__(256) void k_bnfin(const float* __restrict__ psum, const float* __restrict__ psq,
                        const float* __restrict__ g, const float* __restrict__ b,
                        float* scale, float* shift, int N){
  __shared__ float rs[256], rq[256];
  int c=blockIdx.x, tid=threadIdx.x;
  rs[tid]=psum[(size_t)tid*DD+c]+psum[(size_t)(tid+256)*DD+c];
  rq[tid]=psq[(size_t)tid*DD+c]+psq[(size_t)(tid+256)*DD+c];
  __syncthreads();
  #pragma unroll
  for(int off=128;off>0;off>>=1){
    if(tid<off){ rs[tid]+=rs[tid+off]; rq[tid]+=rq[tid+off]; }
    __syncthreads();
  }
  if(tid==0){
    float inv=1.f/(float)N;
    float mu=rs[0]*inv;
    float var=rq[0]*inv - mu*mu;
    float sc=g[c]*rsqrtf(var+1e-5f);
    scale[c]=sc;
    shift[c]=b[c]-mu*sc;
  }
}

// out = relu(h*scale + shift [+ res]); wave-per-row, float4, shuffle-reduced a_i (no LDS).
#define NB_BA 1024
template<bool RES, bool CVT>
__global__ __launch_bounds__(256) void k_bnapply(const float* __restrict__ hm, const float* __restrict__ scale,
                          const float* __restrict__ shift, const float* __restrict__ res,
                          float* __restrict__ outp, unsigned short* __restrict__ xb,
                          const float* __restrict__ wd_as, float* __restrict__ a_i, int N){
  int b=blockIdx.x, tid=threadIdx.x, wv=tid>>6, l=tid&63;
  int c0=4*l;
  float4 sc=*(const float4*)&scale[c0];
  float4 sh=*(const float4*)&shift[c0];
  float wa[4][8];
  if(CVT){
    #pragma unroll
    for(int j=0;j<4;j++)
      #pragma unroll
      for(int h=0;h<8;h++) wa[j][h]=wd_as[(c0+j)*8+h];
  }
  for(int n=b*4+wv; n<N; n+=NB_BA*4){
    float4 v=*(const float4*)&hm[(size_t)n*DD+c0];
    v.x=v.x*sc.x+sh.x; v.y=v.y*sc.y+sh.y; v.z=v.z*sc.z+sh.z; v.w=v.w*sc.w+sh.w;
    if(RES){
      float4 rr=*(const float4*)&res[(size_t)n*DD+c0];
      v.x+=rr.x; v.y+=rr.y; v.z+=rr.z; v.w+=rr.w;
    }
    v.x=fmaxf(v.x,0.f); v.y=fmaxf(v.y,0.f); v.z=fmaxf(v.z,0.f); v.w=fmaxf(v.w,0.f);
    *(float4*)&outp[(size_t)n*DD+c0]=v;
    if(CVT){
      ushort4 xo; xo.x=f2b(v.x); xo.y=f2b(v.y); xo.z=f2b(v.z); xo.w=f2b(v.w);
      *(ushort4*)&xb[(size_t)n*DD+c0]=xo;
      float ai[8];
      #pragma unroll
      for(int h=0;h<8;h++) ai[h]=v.x*wa[0][h]+v.y*wa[1][h]+v.z*wa[2][h]+v.w*wa[3][h];
      #pragma unroll
      for(int off=1;off<64;off<<=1){
        #pragma unroll
        for(int h=0;h<8;h++) ai[h]+=__shfl_xor(ai[h],off);
      }
      if(l==0){
        float4 A; A.x=ai[0];A.y=ai[1];A.z=ai[2];A.w=ai[3];
        float4 B; B.x=ai[4];B.y=ai[5];B.z=ai[6];B.w=ai[7];
        *(float4*)&a_i[(size_t)n*HH]=A;
        *(float4*)&a_i[(size_t)n*HH+4]=B;
      }
    }
  }
}

extern "C" void kernel_launch(void* const* d_in, const int* in_sizes, int n_in,
                              void* d_out, int out_size, void* d_ws, size_t ws_size,
                              hipStream_t stream) {
  const float* x  = (const float*)d_in[0];
  const int*   ei = (const int*)d_in[1];
  const float* ea = (const float*)d_in[2];
  const int*   et = (const int*)d_in[3];
  int N = in_sizes[0]/DD;
  int E = in_sizes[3];
  int Etot = E+N;
  const int* srcE = ei;
  const int* dstE = ei + E;

  const float* Ws1=(const float*)d_in[4];  const float* Wd1=(const float*)d_in[5];
  const float* as1=(const float*)d_in[6];  const float* ad1=(const float*)d_in[7];
  const float* We1=(const float*)d_in[8];  const float* ae1=(const float*)d_in[9];
  const float* te1=(const float*)d_in[10]; const float* Wo1=(const float*)d_in[11];
  const float* bo1=(const float*)d_in[12]; const float* b1 =(const float*)d_in[13];
  const float* lg1=(const float*)d_in[14]; const float* lb1=(const float*)d_in[15];
  const float* Ws2=(const float*)d_in[16]; const float* Wd2=(const float*)d_in[17];
  const float* as2=(const float*)d_in[18]; const float* ad2=(const float*)d_in[19];
  const float* We2=(const float*)d_in[20]; const float* ae2=(const float*)d_in[21];
  const float* te2=(const float*)d_in[22]; const float* Wo2=(const float*)d_in[23];
  const float* bo2=(const float*)d_in[24]; const float* b2 =(const float*)d_in[25];
  const float* lg2=(const float*)d_in[26]; const float* lb2=(const float*)d_in[27];
  const float* bng1=(const float*)d_in[28]; const float* bnb1=(const float*)d_in[29];
  const float* bng2=(const float*)d_in[30]; const float* bnb2=(const float*)d_in[31];

  char* p=(char*)d_ws;
  auto alloc=[&](size_t bytes)->void*{ void* r=(void*)p; p+=(bytes+255)&~(size_t)255; return r; };
  unsigned short* xb   =(unsigned short*)alloc((size_t)N*DD*2);
  unsigned short* ysb  =(unsigned short*)alloc((size_t)N*DD*2);
  unsigned short* aggb =(unsigned short*)alloc((size_t)N*DD*2);
  float* Sreg  =(float*)alloc((size_t)N*DD*4);        // alphaP (Etot*8*4=10.9MB) then z (20.5MB)
  float* xout1 =(float*)alloc((size_t)N*DD*4);
  float* a_i   =(float*)alloc((size_t)N*HH*4);
  float* a_j   =(float*)alloc((size_t)N*HH*4);
  float* wd_as1=(float*)alloc(DD*HH*4);
  float* v_e1  =(float*)alloc(16*HH*4);
  float* t_a1  =(float*)alloc(7*HH*4);
  float* wd_as2=(float*)alloc(DD*HH*4);
  float* v_e2  =(float*)alloc(16*HH*4);
  float* t_a2  =(float*)alloc(7*HH*4);
  float* psum  =(float*)alloc((size_t)NB_LN*DD*4);
  float* psq   =(float*)alloc((size_t)NB_LN*DD*4);
  float* scl   =(float*)alloc(256*4);
  float* shf   =(float*)alloc(256*4);
  unsigned short* Wsb1T=(unsigned short*)alloc((size_t)DD*DD*2);
  unsigned short* Wob1T=(unsigned short*)alloc((size_t)DD*DD*2);
  unsigned short* Wsb2T=(unsigned short*)alloc((size_t)DD*DD*2);
  unsigned short* Wob2T=(unsigned short*)alloc((size_t)DD*DD*2);
  int* cnt     =(int*)alloc((size_t)N*4);
  int* row_off =(int*)alloc((size_t)(N+1)*4);
  int* cursor  =(int*)alloc((size_t)N*4);
  int* epos    =(int*)alloc((size_t)Etot*4);
  int* esrc    =(int*)alloc((size_t)Etot*4);
  float* hbuf  =(float*)d_out;
  float* alphaP=Sreg;
  float* zbuf=Sreg;

  dim3 gg(2,(N+127)/128);
  int aggGrid=(N+3)/4;

  // upfront: CSR + weight prep (both layers)
  k_zero_i<<<(N+255)/256,256,0,stream>>>(cnt,N);
  k_count<<<(Etot+255)/256,256,0,stream>>>(dstE,E,N,cnt);
  k_scan<<<1,1024,0,stream>>>(cnt,N,row_off,cursor);
  k_fill<<<(Etot+255)/256,256,0,stream>>>(srcE,dstE,E,N,cursor,epos,esrc);
  k_cvt_wT<<<DD,DD,0,stream>>>(Ws1,Wsb1T);
  k_cvt_wT<<<DD,DD,0,stream>>>(Wo1,Wob1T);
  k_cvt_wT<<<DD,DD,0,stream>>>(Ws2,Wsb2T);
  k_cvt_wT<<<DD,DD,0,stream>>>(Wo2,Wob2T);
  k_pre<<<1,256,0,stream>>>(Wd1,as1,We1,ae1,te1,wd_as1,v_e1,t_a1);
  k_pre<<<1,256,0,stream>>>(Wd2,as2,We2,ae2,te2,wd_as2,v_e2,t_a2);

  // ---- layer 1 ----
  k_cvt_x<<<N,256,0,stream>>>(x,wd_as1,xb,a_i,N);
  k_gemm_mfma<true,false><<<gg,256,0,stream>>>(xb,Wsb1T,nullptr,nullptr,(void*)ysb,N);
  k_aj<<<N,256,0,stream>>>(ysb,ad1,a_j,N);
  k_edge<<<(Etot+255)/256,256,0,stream>>>(srcE,dstE,ea,et,epos,a_i,a_j,v_e1,t_a1,alphaP,E,N);
  k_agg<<<aggGrid,256,0,stream>>>(row_off,esrc,alphaP,ysb,aggb,N);
  k_gemm_mfma<false,true><<<gg,256,0,stream>>>(aggb,Wob1T,bo1,b1,(void*)zbuf,N);
  k_lnbn<<<NB_LN,256,0,stream>>>(zbuf,x,lg1,lb1,hbuf,psum,psq,N);
  k_bnfin<<<DD,256,0,stream>>>(psum,psq,bng1,bnb1,scl,shf,N);
  k_bnapply<false,true><<<NB_BA,256,0,stream>>>(hbuf,scl,shf,nullptr,xout1,xb,wd_as2,a_i,N);

  // ---- layer 2 ----
  k_gemm_mfma<true,false><<<gg,256,0,stream>>>(xb,Wsb2T,nullptr,nullptr,(void*)ysb,N);
  k_aj<<<N,256,0,stream>>>(ysb,ad2,a_j,N);
  k_edge<<<(Etot+255)/256,256,0,stream>>>(srcE,dstE,ea,et,epos,a_i,a_j,v_e2,t_a2,alphaP,E,N);
  k_agg<<<aggGrid,256,0,stream>>>(row_off,esrc,alphaP,ysb,aggb,N);
  k_gemm_mfma<false,true><<<gg,256,0,stream>>>(aggb,Wob2T,bo2,b2,(void*)zbuf,N);
  k_lnbn<<<NB_LN,256,0,stream>>>(zbuf,xout1,lg2,lb2,hbuf,psum,psq,N);
  k_bnfin<<<DD,256,0,stream>>>(psum,psq,bng2,bnb2,scl,shf,N);
  k_bnapply<true,false><<<NB_BA,256,0,stream>>>(hbuf,scl,shf,x,(float*)d_out,nullptr,nullptr,nullptr,N);
}

// Round 8
// 321.593 us; speedup vs baseline: 1.8254x; 1.1413x over previous
//
#include <hip/hip_runtime.h>

#define DD 256
#define HH 8
#define CC 32

typedef __attribute__((ext_vector_type(8))) short short8;
typedef __attribute__((ext_vector_type(4))) float f32x4;

static __device__ __forceinline__ unsigned short f2b(float f){
  unsigned u = __float_as_uint(f);
  u = u + 0x7FFFu + ((u >> 16) & 1u);          // RNE
  return (unsigned short)(u >> 16);
}
static __device__ __forceinline__ float b2f(unsigned short s){
  return __uint_as_float(((unsigned)s) << 16);
}

// ---------------- utility ----------------
__global__ void k_zero_i(int* p, int n){ int i=blockIdx.x*blockDim.x+threadIdx.x; if(i<n) p[i]=0; }

// ---------------- CSR build ----------------
__global__ void k_count(const int* __restrict__ dstE, int E, int N, int* cnt){
  int e=blockIdx.x*blockDim.x+threadIdx.x;
  if(e<E+N){ int d=(e<E)? dstE[e] : (e-E); atomicAdd(&cnt[d],1); }
}

__global__ __launch_bounds__(1024) void k_scan(const int* __restrict__ cnt, int N, int* row_off, int* cursor){
  __shared__ int part[1024];
  int t=threadIdx.x;
  int chunk=(N+1023)>>10;
  int s=0;
  for(int j=0;j<chunk;j++){ int i=t*chunk+j; if(i<N) s+=cnt[i]; }
  part[t]=s; __syncthreads();
  for(int off=1; off<1024; off<<=1){
    int v=(t>=off)? part[t-off]:0;
    __syncthreads();
    part[t]+=v;
    __syncthreads();
  }
  int run=(t==0)?0:part[t-1];
  for(int j=0;j<chunk;j++){ int i=t*chunk+j; if(i<N){ row_off[i]=run; cursor[i]=run; run+=cnt[i]; } }
  if(t==1023) row_off[N]=part[1023];
}

// emits e->pos mapping (epos) and CSR-ordered sources (esrc)
__global__ void k_fill(const int* __restrict__ srcE, const int* __restrict__ dstE, int E, int N,
                       int* cursor, int* epos, int* esrc){
  int e=blockIdx.x*blockDim.x+threadIdx.x;
  if(e>=E+N) return;
  int s,d;
  if(e<E){ s=srcE[e]; d=dstE[e]; } else { s=e-E; d=s; }
  int pos=atomicAdd(&cursor[d],1);
  epos[e]=pos; esrc[pos]=s;
}

// ---------------- 4x weight transpose + bf16 convert in one launch ----------------
__global__ void k_cvt_wT4(const float* __restrict__ W0, const float* __restrict__ W1,
                          const float* __restrict__ W2, const float* __restrict__ W3,
                          unsigned short* __restrict__ T0, unsigned short* __restrict__ T1,
                          unsigned short* __restrict__ T2, unsigned short* __restrict__ T3){
  int m=blockIdx.y, c=blockIdx.x, k=threadIdx.x;
  const float* W = (m==0)?W0:(m==1)?W1:(m==2)?W2:W3;
  unsigned short* T = (m==0)?T0:(m==1)?T1:(m==2)?T2:T3;
  T[(size_t)c*DD+k] = f2b(W[(size_t)k*DD+c]);
}

// ---------------- folded logit weights (both layers, one launch) ----------------
__global__ void k_pre2(const float* __restrict__ Wd1, const float* __restrict__ as1,
                       const float* __restrict__ We1, const float* __restrict__ ae1,
                       const float* __restrict__ te1,
                       const float* __restrict__ Wd2, const float* __restrict__ as2,
                       const float* __restrict__ We2, const float* __restrict__ ae2,
                       const float* __restrict__ te2,
                       float* wd_as1, float* v_e1, float* t_a1,
                       float* wd_as2, float* v_e2, float* t_a2){
  int L=blockIdx.x;
  const float* Wd=L?Wd2:Wd1; const float* as_=L?as2:as1;
  const float* We=L?We2:We1; const float* ae=L?ae2:ae1; const float* te=L?te2:te1;
  float* wd_as=L?wd_as2:wd_as1; float* v_e=L?v_e2:v_e1; float* t_a=L?t_a2:t_a1;
  int t=threadIdx.x;
  for(int idx=t; idx<DD*HH; idx+=256){
    int k=idx>>3, h=idx&7;
    const float* w=&Wd[k*DD+h*CC]; const float* a=&as_[h*CC];
    float s=0;
    #pragma unroll
    for(int c=0;c<CC;c++) s+=w[c]*a[c];
    wd_as[idx]=s;
  }
  for(int idx=t; idx<16*HH; idx+=256){
    int k=idx>>3, h=idx&7;
    const float* w=&We[k*DD+h*CC]; const float* a=&ae[h*CC];
    float s=0;
    #pragma unroll
    for(int c=0;c<CC;c++) s+=w[c]*a[c];
    v_e[idx]=s;
  }
  for(int idx=t; idx<7*HH; idx+=256){
    int k=idx>>3, h=idx&7;
    const float* w=&te[k*DD+h*CC]; const float* a=&ae[h*CC];
    float s=0;
    #pragma unroll
    for(int c=0;c<CC;c++) s+=w[c]*a[c];
    t_a[idx]=s;
  }
}

// ---------------- x -> bf16 + a_i = x @ wd_as ----------------
__global__ __launch_bounds__(256) void k_cvt_x(const float* __restrict__ xin, const float* __restrict__ wd_as,
                        unsigned short* __restrict__ xb, float* __restrict__ a_i, int N){
  __shared__ float red[DD*HH];     // [k][h] 8KB
  __shared__ float part[8][8];
  int n=blockIdx.x, tid=threadIdx.x;
  float v=xin[(size_t)n*DD+tid];
  xb[(size_t)n*DD+tid]=f2b(v);
  #pragma unroll
  for(int h=0;h<HH;h++) red[tid*HH+h]=v*wd_as[tid*HH+h];
  __syncthreads();
  if(tid<64){
    int h=tid&7, ch=tid>>3;
    float s=0.f;
    for(int k=ch*32;k<ch*32+32;k++) s+=red[k*HH+h];
    part[ch][h]=s;
  }
  __syncthreads();
  if(tid<8){
    float s=0.f;
    #pragma unroll
    for(int ch=0;ch<8;ch++) s+=part[ch][tid];
    a_i[(size_t)n*HH+tid]=s;
  }
}

// ---------------- bf16 MFMA GEMM: C[N,256] = A_bf16[N,256] @ B (Bt = B^T bf16) ----------------
// tile 64x128, BK=32, 4 waves; wave w -> rows 0..63 x cols [32w,32w+32), 4x2 MFMA frags.
// 626 blocks -> ~2.4 blocks/CU (load balance). Register-prefetch pipeline; XOR-granule swizzle.
// AJ: fuse a_j[row][head] = sum_col acc*ad[col] for head = blockIdx.x*4+w (cols 32w..32w+31).
template<bool OUTBF16, bool BIAS, bool AJ>
__global__ __launch_bounds__(256) void k_gemm_mfma(const unsigned short* __restrict__ A,
                                                   const unsigned short* __restrict__ Bt,
                                                   const float* __restrict__ bia1, const float* __restrict__ bia2,
                                                   const float* __restrict__ ad, float* __restrict__ a_j,
                                                   void* __restrict__ Cout, int N){
  __shared__ char lds[4096 + 8192];   // As 64x32 (4KB) + Bs 128x32 (8KB)
  int tid=threadIdx.x;
  int w=tid>>6, l=tid&63;
  int row0=blockIdx.y*64, col0=blockIdx.x*128;

  int sr=tid>>2, skc=tid&3;
  int kcs=skc^((sr>>1)&3);
  int aslot=sr*4+skc;
  int bslot1=sr*4+skc, bslot2=(sr+64)*4+skc;
  int gr=row0+sr;
  size_t boff1=(size_t)(col0+sr)*DD, boff2=(size_t)(col0+64+sr)*DD;

  int x15=l&15;
  int lp=x15*64 + ((l>>4)^((x15>>1)&3))*16;

  f32x4 acc[4][2];
  #pragma unroll
  for(int i=0;i<4;i++){ acc[i][0]=(f32x4)0.f; acc[i][1]=(f32x4)0.f; }

  const short8 zero8=(short8)0;
  short8 av,bv1,bv2;
  av  = (gr<N) ? *(const short8*)&A[(size_t)gr*DD + kcs*8] : zero8;
  bv1 = *(const short8*)&Bt[boff1 + kcs*8];
  bv2 = *(const short8*)&Bt[boff2 + kcs*8];

  for(int kt=0;kt<DD;kt+=32){
    __syncthreads();
    *(short8*)(lds + aslot*16) = av;
    *(short8*)(lds + 4096 + bslot1*16) = bv1;
    *(short8*)(lds + 4096 + bslot2*16) = bv2;
    __syncthreads();
    if(kt+32<DD){
      int ko=kt+32+kcs*8;
      av  = (gr<N) ? *(const short8*)&A[(size_t)gr*DD + ko] : zero8;
      bv1 = *(const short8*)&Bt[boff1 + ko];
      bv2 = *(const short8*)&Bt[boff2 + ko];
    }
    short8 af[4], bf[2];
    #pragma unroll
    for(int mf=0;mf<4;mf++) af[mf]=*(short8*)(lds + mf*1024 + lp);
    #pragma unroll
    for(int nf=0;nf<2;nf++) bf[nf]=*(short8*)(lds + 4096 + (32*w+16*nf)*64 + lp);
    #pragma unroll
    for(int mf=0;mf<4;mf++)
      #pragma unroll
      for(int nf=0;nf<2;nf++)
        acc[mf][nf]=__builtin_amdgcn_mfma_f32_16x16x32_bf16(af[mf],bf[nf],acc[mf][nf],0,0,0);
  }

  int lcol=x15, lrow4=(l>>4)*4;
  float ad0=0.f, ad1=0.f;
  if(AJ){ ad0=ad[col0+32*w+lcol]; ad1=ad[col0+32*w+16+lcol]; }
  int head=(col0>>5)+w;   // col0 is 0 or 128 -> heads 0..3 / 4..7
  #pragma unroll
  for(int mf=0;mf<4;mf++){
    #pragma unroll
    for(int nf=0;nf<2;nf++){
      int col=col0 + 32*w + 16*nf + lcol;
      float badd = BIAS ? (bia1[col]+bia2[col]) : 0.f;
      #pragma unroll
      for(int rr=0;rr<4;rr++){
        int row=row0 + 16*mf + lrow4 + rr;
        if(row<N){
          float v=acc[mf][nf][rr]+badd;
          if(OUTBF16) ((unsigned short*)Cout)[(size_t)row*DD+col]=f2b(v);
          else        ((float*)Cout)[(size_t)row*DD+col]=v;
        }
      }
    }
    if(AJ){
      #pragma unroll
      for(int rr=0;rr<4;rr++){
        float t=acc[mf][0][rr]*ad0 + acc[mf][1][rr]*ad1;
        t+=__shfl_xor(t,1); t+=__shfl_xor(t,2);
        t+=__shfl_xor(t,4); t+=__shfl_xor(t,8);
        int row=row0 + 16*mf + lrow4 + rr;
        if(x15==0 && row<N) a_j[(size_t)row*HH+head]=t;
      }
    }
  }
}

// ---------------- edge logits, written in CSR (dst-sorted) order ----------------
__global__ void k_edge(const int* __restrict__ srcE, const int* __restrict__ dstE,
                       const float* __restrict__ ea, const int* __restrict__ et,
                       const int* __restrict__ epos,
                       const float* __restrict__ a_i, const float* __restrict__ a_j,
                       const float* __restrict__ v_e, const float* __restrict__ t_a,
                       float* __restrict__ alphaP, int E, int N){
  int e=blockIdx.x*blockDim.x+threadIdx.x;
  if(e>=E+N) return;
  int s,d,ty;
  float eattr[16];
  if(e<E){
    s=srcE[e]; d=dstE[e]; ty=et[e];
    float4 q0=*(const float4*)&ea[(size_t)e*16+0];
    float4 q1=*(const float4*)&ea[(size_t)e*16+4];
    float4 q2=*(const float4*)&ea[(size_t)e*16+8];
    float4 q3=*(const float4*)&ea[(size_t)e*16+12];
    eattr[0]=q0.x;eattr[1]=q0.y;eattr[2]=q0.z;eattr[3]=q0.w;
    eattr[4]=q1.x;eattr[5]=q1.y;eattr[6]=q1.z;eattr[7]=q1.w;
    eattr[8]=q2.x;eattr[9]=q2.y;eattr[10]=q2.z;eattr[11]=q2.w;
    eattr[12]=q3.x;eattr[13]=q3.y;eattr[14]=q3.z;eattr[15]=q3.w;
  }else{
    s=e-E; d=s; ty=6;
    #pragma unroll
    for(int k=0;k<16;k++) eattr[k]=1.f;
  }
  int pos=epos[e];
  const float* ai=&a_i[(size_t)d*8];
  const float* aj=&a_j[(size_t)s*8];
  #pragma unroll
  for(int h=0;h<8;h++){
    float v=ai[h]+aj[h]+t_a[ty*8+h];
    #pragma unroll
    for(int k=0;k<16;k++) v+=eattr[k]*v_e[k*8+h];
    alphaP[(size_t)pos*8+h] = (v>=0.f)? v : 0.2f*v;
  }
}

// ---------------- segment softmax + aggregation: ONE WAVE PER NODE ----------------
// pass1: coalesced alphaP stream max. pass2: chunk-of-8 with software-pipelined
// alpha/esrc loads (next chunk prefetched before current gather consumes).
__global__ __launch_bounds__(256) void k_agg(const int* __restrict__ row_off,
                      const int* __restrict__ esrc, const float* __restrict__ alphaP,
                      const unsigned short* __restrict__ ysb, unsigned short* __restrict__ aggb, int N){
  int wv=threadIdx.x>>6, l=threadIdx.x&63;
  int n=blockIdx.x*4+wv;
  if(n>=N) return;
  int beg=row_off[n], deg=row_off[n+1]-beg;
  int slotL=l>>3, headL=l&7;
  float mx=-3e38f;
  for(int i=slotL;i<deg;i+=8) mx=fmaxf(mx, alphaP[(size_t)(beg+i)*8+headL]);
  mx=fmaxf(mx,__shfl_xor(mx,8));
  mx=fmaxf(mx,__shfl_xor(mx,16));
  mx=fmaxf(mx,__shfl_xor(mx,32));
  int ghead=l>>3;
  float ssum=0.f, acc0=0.f, acc1=0.f, acc2=0.f, acc3=0.f;
  // initial chunk load (deg>=1 guaranteed: self-loop)
  float a_c; int s_c;
  {
    int i=slotL; bool ok=(i<deg); int ic=ok?i:(deg-1);
    a_c = ok ? alphaP[(size_t)(beg+i)*8+headL] : -3e38f;
    s_c = esrc[beg+ic];
  }
  for(int base=0;base<deg;base+=8){
    float a_n=-3e38f; int s_n=0;
    if(base+8<deg){
      int i=base+8+slotL; bool ok=(i<deg); int ic=ok?i:(deg-1);
      a_n = ok ? alphaP[(size_t)(beg+i)*8+headL] : -3e38f;
      s_n = esrc[beg+ic];
    }
    float wvv=__expf(a_c-mx);
    int cnt=min(8,deg-base);
    #pragma unroll
    for(int u=0;u<8;u++){
      if(u<cnt){
        float wgt=__shfl(wvv,(u<<3)|ghead);
        int   si =__shfl(s_c,(u<<3));
        ssum+=wgt;
        ushort4 y=*(const ushort4*)&ysb[(size_t)si*DD+4*l];
        acc0+=wgt*b2f(y.x); acc1+=wgt*b2f(y.y); acc2+=wgt*b2f(y.z); acc3+=wgt*b2f(y.w);
      }
    }
    a_c=a_n; s_c=s_n;
  }
  float inv=1.f/(ssum+1e-16f);
  ushort4 o;
  o.x=f2b(acc0*inv); o.y=f2b(acc1*inv); o.z=f2b(acc2*inv); o.w=f2b(acc3*inv);
  *(ushort4*)&aggb[(size_t)n*DD+4*l]=o;
}

// ---------------- fused LayerNorm + residual + BN column partials ----------------
#define NB_LN 512
__global__ __launch_bounds__(256) void k_lnbn(const float* __restrict__ z, const float* __restrict__ xin,
                         const float* __restrict__ lg, const float* __restrict__ lb,
                         float* __restrict__ hout, float* __restrict__ psum, float* __restrict__ psq, int N){
  __shared__ float sps[4][DD], spq[4][DD];
  int b=blockIdx.x, tid=threadIdx.x, wv=tid>>6, l=tid&63;
  int c0=4*l;
  float4 lgv=*(const float4*)&lg[c0];
  float4 lbv=*(const float4*)&lb[c0];
  float ps0=0.f,ps1=0.f,ps2=0.f,ps3=0.f,pq0=0.f,pq1=0.f,pq2=0.f,pq3=0.f;
  for(int r=b*4+wv; r<N; r+=NB_LN*4){
    float4 v=*(const float4*)&z[(size_t)r*DD+c0];
    float s=v.x+v.y+v.z+v.w;
    float q=v.x*v.x+v.y*v.y+v.z*v.z+v.w*v.w;
    #pragma unroll
    for(int off=1;off<64;off<<=1){ s+=__shfl_xor(s,off); q+=__shfl_xor(q,off); }
    float mu=s*(1.f/DD);
    float var=q*(1.f/DD)-mu*mu;
    float rstd=rsqrtf(var+1e-5f);
    float4 xr=*(const float4*)&xin[(size_t)r*DD+c0];
    float4 h;
    h.x=(v.x-mu)*rstd*lgv.x+lbv.x+xr.x;
    h.y=(v.y-mu)*rstd*lgv.y+lbv.y+xr.y;
    h.z=(v.z-mu)*rstd*lgv.z+lbv.z+xr.z;
    h.w=(v.w-mu)*rstd*lgv.w+lbv.w+xr.w;
    *(float4*)&hout[(size_t)r*DD+c0]=h;
    ps0+=h.x;ps1+=h.y;ps2+=h.z;ps3+=h.w;
    pq0+=h.x*h.x;pq1+=h.y*h.y;pq2+=h.z*h.z;pq3+=h.w*h.w;
  }
  sps[wv][c0+0]=ps0; sps[wv][c0+1]=ps1; sps[wv][c0+2]=ps2; sps[wv][c0+3]=ps3;
  spq[wv][c0+0]=pq0; spq[wv][c0+1]=pq1; spq[wv][c0+2]=pq2; spq[wv][c0+3]=pq3;
  __syncthreads();
  float s=sps[0][tid]+sps[1][tid]+sps[2][tid]+sps[3][tid];
  float q=spq[0][tid]+spq[1][tid]+spq[2][tid]+spq[3][tid];
  psum[(size_t)b*DD+tid]=s;
  psq[(size_t)b*DD+tid]=q;
}

// ---------------- BN finalize from partials: one block PER COLUMN (NB_LN=512 partials) ----------------
__global__ __launch_bounds__(256) void k_bnfin(const float* __restrict__ psum, const float* __restrict__ psq,
                        const float* __restrict__ g, const float* __restrict__ b,
                        float* scale, float* shift, int N){
  __shared__ float rs[256], rq[256];
  int c=blockIdx.x, tid=threadIdx.x;
  rs[tid]=psum[(size_t)tid*DD+c]+psum[(size_t)(tid+256)*DD+c];
  rq[tid]=psq[(size_t)tid*DD+c]+psq[(size_t)(tid+256)*DD+c];
  __syncthreads();
  #pragma unroll
  for(int off=128;off>0;off>>=1){
    if(tid<off){ rs[tid]+=rs[tid+off]; rq[tid]+=rq[tid+off]; }
    __syncthreads();
  }
  if(tid==0){
    float inv=1.f/(float)N;
    float mu=rs[0]*inv;
    float var=rq[0]*inv - mu*mu;
    float sc=g[c]*rsqrtf(var+1e-5f);
    scale[c]=sc;
    shift[c]=b[c]-mu*sc;
  }
}

// out = relu(h*scale + shift [+ res]); wave-per-row, float4, shuffle-reduced a_i (no LDS).
#define NB_BA 1024
template<bool RES, bool CVT>
__global__ __launch_bounds__(256) void k_bnapply(const float* __restrict__ hm, const float* __restrict__ scale,
                          const float* __restrict__ shift, const float* __restrict__ res,
                          float* __restrict__ outp, unsigned short* __restrict__ xb,
                          const float* __restrict__ wd_as, float* __restrict__ a_i, int N){
  int b=blockIdx.x, tid=threadIdx.x, wv=tid>>6, l=tid&63;
  int c0=4*l;
  float4 sc=*(const float4*)&scale[c0];
  float4 sh=*(const float4*)&shift[c0];
  float wa[4][8];
  if(CVT){
    #pragma unroll
    for(int j=0;j<4;j++)
      #pragma unroll
      for(int h=0;h<8;h++) wa[j][h]=wd_as[(c0+j)*8+h];
  }
  for(int n=b*4+wv; n<N; n+=NB_BA*4){
    float4 v=*(const float4*)&hm[(size_t)n*DD+c0];
    v.x=v.x*sc.x+sh.x; v.y=v.y*sc.y+sh.y; v.z=v.z*sc.z+sh.z; v.w=v.w*sc.w+sh.w;
    if(RES){
      float4 rr=*(const float4*)&res[(size_t)n*DD+c0];
      v.x+=rr.x; v.y+=rr.y; v.z+=rr.z; v.w+=rr.w;
    }
    v.x=fmaxf(v.x,0.f); v.y=fmaxf(v.y,0.f); v.z=fmaxf(v.z,0.f); v.w=fmaxf(v.w,0.f);
    *(float4*)&outp[(size_t)n*DD+c0]=v;
    if(CVT){
      ushort4 xo; xo.x=f2b(v.x); xo.y=f2b(v.y); xo.z=f2b(v.z); xo.w=f2b(v.w);
      *(ushort4*)&xb[(size_t)n*DD+c0]=xo;
      float ai[8];
      #pragma unroll
      for(int h=0;h<8;h++) ai[h]=v.x*wa[0][h]+v.y*wa[1][h]+v.z*wa[2][h]+v.w*wa[3][h];
      #pragma unroll
      for(int off=1;off<64;off<<=1){
        #pragma unroll
        for(int h=0;h<8;h++) ai[h]+=__shfl_xor(ai[h],off);
      }
      if(l==0){
        float4 A; A.x=ai[0];A.y=ai[1];A.z=ai[2];A.w=ai[3];
        float4 B; B.x=ai[4];B.y=ai[5];B.z=ai[6];B.w=ai[7];
        *(float4*)&a_i[(size_t)n*HH]=A;
        *(float4*)&a_i[(size_t)n*HH+4]=B;
      }
    }
  }
}

extern "C" void kernel_launch(void* const* d_in, const int* in_sizes, int n_in,
                              void* d_out, int out_size, void* d_ws, size_t ws_size,
                              hipStream_t stream) {
  const float* x  = (const float*)d_in[0];
  const int*   ei = (const int*)d_in[1];
  const float* ea = (const float*)d_in[2];
  const int*   et = (const int*)d_in[3];
  int N = in_sizes[0]/DD;
  int E = in_sizes[3];
  int Etot = E+N;
  const int* srcE = ei;
  const int* dstE = ei + E;

  const float* Ws1=(const float*)d_in[4];  const float* Wd1=(const float*)d_in[5];
  const float* as1=(const float*)d_in[6];  const float* ad1=(const float*)d_in[7];
  const float* We1=(const float*)d_in[8];  const float* ae1=(const float*)d_in[9];
  const float* te1=(const float*)d_in[10]; const float* Wo1=(const float*)d_in[11];
  const float* bo1=(const float*)d_in[12]; const float* b1 =(const float*)d_in[13];
  const float* lg1=(const float*)d_in[14]; const float* lb1=(const float*)d_in[15];
  const float* Ws2=(const float*)d_in[16]; const float* Wd2=(const float*)d_in[17];
  const float* as2=(const float*)d_in[18]; const float* ad2=(const float*)d_in[19];
  const float* We2=(const float*)d_in[20]; const float* ae2=(const float*)d_in[21];
  const float* te2=(const float*)d_in[22]; const float* Wo2=(const float*)d_in[23];
  const float* bo2=(const float*)d_in[24]; const float* b2 =(const float*)d_in[25];
  const float* lg2=(const float*)d_in[26]; const float* lb2=(const float*)d_in[27];
  const float* bng1=(const float*)d_in[28]; const float* bnb1=(const float*)d_in[29];
  const float* bng2=(const float*)d_in[30]; const float* bnb2=(const float*)d_in[31];

  char* p=(char*)d_ws;
  auto alloc=[&](size_t bytes)->void*{ void* r=(void*)p; p+=(bytes+255)&~(size_t)255; return r; };
  unsigned short* xb   =(unsigned short*)alloc((size_t)N*DD*2);
  unsigned short* ysb  =(unsigned short*)alloc((size_t)N*DD*2);
  unsigned short* aggb =(unsigned short*)alloc((size_t)N*DD*2);
  float* Sreg  =(float*)alloc((size_t)N*DD*4);        // alphaP (Etot*8*4=10.9MB) then z (20.5MB)
  float* xout1 =(float*)alloc((size_t)N*DD*4);
  float* a_i   =(float*)alloc((size_t)N*HH*4);
  float* a_j   =(float*)alloc((size_t)N*HH*4);
  float* wd_as1=(float*)alloc(DD*HH*4);
  float* v_e1  =(float*)alloc(16*HH*4);
  float* t_a1  =(float*)alloc(7*HH*4);
  float* wd_as2=(float*)alloc(DD*HH*4);
  float* v_e2  =(float*)alloc(16*HH*4);
  float* t_a2  =(float*)alloc(7*HH*4);
  float* psum  =(float*)alloc((size_t)NB_LN*DD*4);
  float* psq   =(float*)alloc((size_t)NB_LN*DD*4);
  float* scl   =(float*)alloc(256*4);
  float* shf   =(float*)alloc(256*4);
  unsigned short* Wsb1T=(unsigned short*)alloc((size_t)DD*DD*2);
  unsigned short* Wob1T=(unsigned short*)alloc((size_t)DD*DD*2);
  unsigned short* Wsb2T=(unsigned short*)alloc((size_t)DD*DD*2);
  unsigned short* Wob2T=(unsigned short*)alloc((size_t)DD*DD*2);
  int* cnt     =(int*)alloc((size_t)N*4);
  int* row_off =(int*)alloc((size_t)(N+1)*4);
  int* cursor  =(int*)alloc((size_t)N*4);
  int* epos    =(int*)alloc((size_t)Etot*4);
  int* esrc    =(int*)alloc((size_t)Etot*4);
  float* hbuf  =(float*)d_out;
  float* alphaP=Sreg;
  float* zbuf=Sreg;

  dim3 gg(2,(N+63)/64);
  int aggGrid=(N+3)/4;

  // upfront: CSR + weight prep (both layers)
  k_zero_i<<<(N+255)/256,256,0,stream>>>(cnt,N);
  k_count<<<(Etot+255)/256,256,0,stream>>>(dstE,E,N,cnt);
  k_scan<<<1,1024,0,stream>>>(cnt,N,row_off,cursor);
  k_fill<<<(Etot+255)/256,256,0,stream>>>(srcE,dstE,E,N,cursor,epos,esrc);
  k_cvt_wT4<<<dim3(DD,4),DD,0,stream>>>(Ws1,Wo1,Ws2,Wo2,Wsb1T,Wob1T,Wsb2T,Wob2T);
  k_pre2<<<2,256,0,stream>>>(Wd1,as1,We1,ae1,te1,Wd2,as2,We2,ae2,te2,
                             wd_as1,v_e1,t_a1,wd_as2,v_e2,t_a2);

  // ---- layer 1 ----
  k_cvt_x<<<N,256,0,stream>>>(x,wd_as1,xb,a_i,N);
  k_gemm_mfma<true,false,true><<<gg,256,0,stream>>>(xb,Wsb1T,nullptr,nullptr,ad1,a_j,(void*)ysb,N);
  k_edge<<<(Etot+255)/256,256,0,stream>>>(srcE,dstE,ea,et,epos,a_i,a_j,v_e1,t_a1,alphaP,E,N);
  k_agg<<<aggGrid,256,0,stream>>>(row_off,esrc,alphaP,ysb,aggb,N);
  k_gemm_mfma<false,true,false><<<gg,256,0,stream>>>(aggb,Wob1T,bo1,b1,nullptr,nullptr,(void*)zbuf,N);
  k_lnbn<<<NB_LN,256,0,stream>>>(zbuf,x,lg1,lb1,hbuf,psum,psq,N);
  k_bnfin<<<DD,256,0,stream>>>(psum,psq,bng1,bnb1,scl,shf,N);
  k_bnapply<false,true><<<NB_BA,256,0,stream>>>(hbuf,scl,shf,nullptr,xout1,xb,wd_as2,a_i,N);

  // ---- layer 2 ----
  k_gemm_mfma<true,false,true><<<gg,256,0,stream>>>(xb,Wsb2T,nullptr,nullptr,ad2,a_j,(void*)ysb,N);
  k_edge<<<(Etot+255)/256,256,0,stream>>>(srcE,dstE,ea,et,epos,a_i,a_j,v_e2,t_a2,alphaP,E,N);
  k_agg<<<aggGrid,256,0,stream>>>(row_off,esrc,alphaP,ysb,aggb,N);
  k_gemm_mfma<false,true,false><<<gg,256,0,stream>>>(aggb,Wob2T,bo2,b2,nullptr,nullptr,(void*)zbuf,N);
  k_lnbn<<<NB_LN,256,0,stream>>>(zbuf,xout1,lg2,lb2,hbuf,psum,psq,N);
  k_bnfin<<<DD,256,0,stream>>>(psum,psq,bng2,bnb2,scl,shf,N);
  k_bnapply<true,false><<<NB_BA,256,0,stream>>>(hbuf,scl,shf,x,(float*)d_out,nullptr,nullptr,nullptr,N);
}